// Round 1
// baseline (1026.413 us; speedup 1.0000x reference)
//
#include <hip/hip_runtime.h>
#include <stdint.h>

#define BN_EPS 1e-5f

// ---------------- CSR build ----------------
__global__ void k_count(const int* __restrict__ dst, int* __restrict__ cnt, int E) {
    int i = blockIdx.x * 256 + threadIdx.x;
    if (i < E) atomicAdd(cnt + dst[i], 1);
}

__global__ void k_invdeg(const int* __restrict__ cnt, float* __restrict__ invd, int N) {
    int i = blockIdx.x * 256 + threadIdx.x;
    if (i < N) invd[i] = 1.0f / fmaxf((float)cnt[i], 1.0f);
}

// single-block exclusive scan of cnt[0..N-1] -> rowptr[0..N]
__global__ void k_scan(const int* __restrict__ cnt, int* __restrict__ rowptr, int N) {
    __shared__ int part[1024];
    int t = threadIdx.x;
    int chunk = (N + 1023) >> 10;
    int lo = t * chunk, hi = min(lo + chunk, N);
    int s = 0;
    for (int i = lo; i < hi; ++i) s += cnt[i];
    part[t] = s;
    __syncthreads();
    for (int off = 1; off < 1024; off <<= 1) {
        int add = (t >= off) ? part[t - off] : 0;
        __syncthreads();
        part[t] += add;
        __syncthreads();
    }
    int run = part[t] - s;  // exclusive prefix
    for (int i = lo; i < hi; ++i) { rowptr[i] = run; run += cnt[i]; }
    if (t == 1023) rowptr[N] = part[1023];
}

__global__ void k_fill(const int* __restrict__ src, const int* __restrict__ dst,
                       const int* __restrict__ rowptr, int* __restrict__ cursor,
                       int* __restrict__ srcs, int E) {
    int i = blockIdx.x * 256 + threadIdx.x;
    if (i < E) {
        int r = dst[i];
        int p = atomicAdd(cursor + r, 1);
        srcs[rowptr[r] + p] = src[i];
    }
}

// ---------------- aggregation: one wave per dst node ----------------
__global__ __launch_bounds__(256) void k_agg(
    const float* __restrict__ x, const int* __restrict__ rowptr,
    const int* __restrict__ srcs, const float* __restrict__ invd,
    float* __restrict__ agg, int N) {
    int gw = (blockIdx.x * blockDim.x + threadIdx.x) >> 6;
    int lane = threadIdx.x & 63;
    if (gw >= N) return;
    int lo = rowptr[gw], hi = rowptr[gw + 1];
    float ax = 0.f, ay = 0.f;
    const float2* x2 = (const float2*)x;
    for (int j = lo; j < hi; ++j) {
        int s = srcs[j];
        float2 v = x2[(size_t)s * 64 + lane];
        ax += v.x; ay += v.y;
    }
    float w = invd[gw];
    float2 o; o.x = ax * w; o.y = ay * w;
    ((float2*)agg)[(size_t)gw * 64 + lane] = o;
}

// ---------------- f32 tiled GEMM: C = [relu]( A@B [+bias] [+res] ) ----------------
// BM=64, BN=64, BK=16, 256 threads, 4x4 micro-tile. K % 16 == 0, Nn % 64 == 0.
template<bool RELU, bool HASB, bool RES>
__global__ __launch_bounds__(256) void k_gemm(
    const float* __restrict__ A, const float* __restrict__ B,
    const float* __restrict__ bias, const float* __restrict__ res,
    float* __restrict__ C, int M, int Nn, int K) {
    __shared__ float As[16][68];
    __shared__ float Bs[16][68];
    int tid = threadIdx.x;
    int row0 = blockIdx.x * 64, col0 = blockIdx.y * 64;
    int lA_m = tid >> 2, lA_k = (tid & 3) << 2;
    int lB_k = tid >> 4, lB_n = (tid & 15) << 2;
    int ty = tid >> 4, tx = tid & 15;
    float acc[4][4] = {};
    for (int k0 = 0; k0 < K; k0 += 16) {
        float4 va = make_float4(0.f, 0.f, 0.f, 0.f);
        int ar = row0 + lA_m;
        if (ar < M) va = *(const float4*)(A + (size_t)ar * K + k0 + lA_k);
        As[lA_k + 0][lA_m] = va.x; As[lA_k + 1][lA_m] = va.y;
        As[lA_k + 2][lA_m] = va.z; As[lA_k + 3][lA_m] = va.w;
        float4 vb = *(const float4*)(B + (size_t)(k0 + lB_k) * Nn + col0 + lB_n);
        *(float4*)&Bs[lB_k][lB_n] = vb;
        __syncthreads();
#pragma unroll
        for (int k = 0; k < 16; ++k) {
            float4 a4 = *(const float4*)&As[k][ty << 2];
            float4 b4 = *(const float4*)&Bs[k][tx << 2];
            float av[4] = {a4.x, a4.y, a4.z, a4.w};
            float bv[4] = {b4.x, b4.y, b4.z, b4.w};
#pragma unroll
            for (int i = 0; i < 4; ++i)
#pragma unroll
                for (int j = 0; j < 4; ++j) acc[i][j] += av[i] * bv[j];
        }
        __syncthreads();
    }
#pragma unroll
    for (int i = 0; i < 4; ++i) {
        int r = row0 + (ty << 2) + i;
        if (r >= M) continue;
        int c = col0 + (tx << 2);
        float4 o = make_float4(acc[i][0], acc[i][1], acc[i][2], acc[i][3]);
        if (HASB) {
            o.x += bias[c]; o.y += bias[c + 1]; o.z += bias[c + 2]; o.w += bias[c + 3];
        }
        if (RES) {
            float4 rv = *(const float4*)(res + (size_t)r * Nn + c);
            o.x += rv.x; o.y += rv.y; o.z += rv.z; o.w += rv.w;
        }
        if (RELU) {
            o.x = fmaxf(o.x, 0.f); o.y = fmaxf(o.y, 0.f);
            o.z = fmaxf(o.z, 0.f); o.w = fmaxf(o.w, 0.f);
        }
        *(float4*)(C + (size_t)r * Nn + c) = o;
    }
}

// ---------------- BatchNorm ----------------
// sums[0..127] = column sums, sums[128..255] = column sumsq (pre-zeroed)
__global__ __launch_bounds__(256) void k_bnstats(const float* __restrict__ t,
                                                 float* __restrict__ sums, int N) {
    __shared__ float ls[256];
    int tid = threadIdx.x;
    ls[tid] = 0.f;
    __syncthreads();
    int c4 = tid & 31, rg = tid >> 5;
    float4 s1 = make_float4(0.f, 0.f, 0.f, 0.f), s2 = make_float4(0.f, 0.f, 0.f, 0.f);
    for (int r = blockIdx.x * 8 + rg; r < N; r += gridDim.x * 8) {
        float4 v = ((const float4*)t)[(size_t)r * 32 + c4];
        s1.x += v.x; s1.y += v.y; s1.z += v.z; s1.w += v.w;
        s2.x += v.x * v.x; s2.y += v.y * v.y; s2.z += v.z * v.z; s2.w += v.w * v.w;
    }
    int c = c4 * 4;
    atomicAdd(&ls[c + 0], s1.x); atomicAdd(&ls[c + 1], s1.y);
    atomicAdd(&ls[c + 2], s1.z); atomicAdd(&ls[c + 3], s1.w);
    atomicAdd(&ls[128 + c + 0], s2.x); atomicAdd(&ls[128 + c + 1], s2.y);
    atomicAdd(&ls[128 + c + 2], s2.z); atomicAdd(&ls[128 + c + 3], s2.w);
    __syncthreads();
    atomicAdd(&sums[tid], ls[tid]);
}

__global__ void k_bnfin(const float* __restrict__ sums, const float* __restrict__ g,
                        const float* __restrict__ b, float* __restrict__ bna,
                        float* __restrict__ bnc, float invN) {
    int c = threadIdx.x;  // 128
    float m = sums[c] * invN;
    float var = sums[128 + c] * invN - m * m;
    float a = g[c] * rsqrtf(var + BN_EPS);
    bna[c] = a;
    bnc[c] = b[c] - m * a;
}

__global__ void k_bnapply(const float* __restrict__ t, const float* __restrict__ bna,
                          const float* __restrict__ bnc, float* __restrict__ xo, int total4) {
    int i = blockIdx.x * 256 + threadIdx.x;
    if (i >= total4) return;
    int c4 = i & 31;
    float4 a = ((const float4*)bna)[c4];
    float4 cc = ((const float4*)bnc)[c4];
    float4 v = ((const float4*)t)[i];
    float4 o;
    o.x = v.x * a.x + cc.x; o.y = v.y * a.y + cc.y;
    o.z = v.z * a.z + cc.z; o.w = v.w * a.w + cc.w;
    ((float4*)xo)[i] = o;
}

// ---------------- classifier: [N,128] @ [128,16] + b ----------------
__global__ __launch_bounds__(256) void k_cls(const float* __restrict__ x,
                                             const float* __restrict__ w,
                                             const float* __restrict__ bias,
                                             float* __restrict__ out, int N) {
    int lane = threadIdx.x & 63;
    int wid = (blockIdx.x * blockDim.x + threadIdx.x) >> 6;
    int nw = (gridDim.x * blockDim.x) >> 6;
    float w0[16], w1[16];
#pragma unroll
    for (int c = 0; c < 16; ++c) {
        w0[c] = w[lane * 16 + c];
        w1[c] = w[(lane + 64) * 16 + c];
    }
    float bv = (lane < 16) ? bias[lane] : 0.f;
    for (int r = wid; r < N; r += nw) {
        float xv0 = x[(size_t)r * 128 + lane];
        float xv1 = x[(size_t)r * 128 + 64 + lane];
        float outv = 0.f;
#pragma unroll
        for (int c = 0; c < 16; ++c) {
            float p = xv0 * w0[c] + xv1 * w1[c];
            p += __shfl_xor(p, 1);  p += __shfl_xor(p, 2);
            p += __shfl_xor(p, 4);  p += __shfl_xor(p, 8);
            p += __shfl_xor(p, 16); p += __shfl_xor(p, 32);
            if (lane == c) outv = p;
        }
        if (lane < 16) out[(size_t)r * 16 + lane] = outv + bv;
    }
}

extern "C" void kernel_launch(void* const* d_in, const int* in_sizes, int n_in,
                              void* d_out, int out_size, void* d_ws, size_t ws_size,
                              hipStream_t stream) {
    const float* nodes = (const float*)d_in[0];
    const float* W_gcn = (const float*)d_in[1];
    const float* b_gcn = (const float*)d_in[2];
    const float* bn1_g = (const float*)d_in[3];
    const float* bn1_b = (const float*)d_in[4];
    const float* bn2_g = (const float*)d_in[5];
    const float* bn2_b = (const float*)d_in[6];
    const float* ff_w1 = (const float*)d_in[7];
    const float* ff_b1 = (const float*)d_in[8];
    const float* ff_w2 = (const float*)d_in[9];
    const float* cls_w = (const float*)d_in[10];
    const float* cls_b = (const float*)d_in[11];
    const int* esrc = (const int*)d_in[12];
    const int* edst = (const int*)d_in[13];
    const int N = in_sizes[0] / 128;
    const int E = in_sizes[12];

    char* p = (char*)d_ws;
    auto alloc = [&](size_t bytes) {
        void* r = (void*)p;
        p += (bytes + 255) & ~(size_t)255;
        return r;
    };
    float* x    = (float*)alloc((size_t)N * 128 * 4);
    float* t    = (float*)alloc((size_t)N * 128 * 4);
    float* agg  = (float*)alloc((size_t)N * 128 * 4);
    float* y    = (float*)alloc((size_t)N * 512 * 4);
    float* invd = (float*)alloc((size_t)N * 4);
    int* cnt    = (int*)alloc((size_t)N * 4);
    int* cursor = (int*)alloc((size_t)N * 4);
    int* rowptr = (int*)alloc((size_t)(N + 1) * 4);
    int* srcs   = (int*)alloc((size_t)E * 4);
    float* sums = (float*)alloc(256 * 4);
    float* bna  = (float*)alloc(128 * 4);
    float* bnc  = (float*)alloc(128 * 4);

    hipMemsetAsync(cnt, 0, (size_t)N * 4, stream);
    hipMemsetAsync(cursor, 0, (size_t)N * 4, stream);
    k_count<<<(E + 255) / 256, 256, 0, stream>>>(edst, cnt, E);
    k_invdeg<<<(N + 255) / 256, 256, 0, stream>>>(cnt, invd, N);
    k_scan<<<1, 1024, 0, stream>>>(cnt, rowptr, N);
    k_fill<<<(E + 255) / 256, 256, 0, stream>>>(esrc, edst, rowptr, cursor, srcs, E);

    const float invN = 1.0f / (float)N;
    const float* cur = nodes;
    for (int L = 0; L < 2; ++L) {
        k_agg<<<(N + 3) / 4, 256, 0, stream>>>(cur, rowptr, srcs, invd, agg, N);
        dim3 g1((N + 63) / 64, 128 / 64);
        k_gemm<false, true, true><<<g1, 256, 0, stream>>>(
            agg, W_gcn + (size_t)L * 128 * 128, b_gcn + L * 128, cur, t, N, 128, 128);
        hipMemsetAsync(sums, 0, 256 * 4, stream);
        k_bnstats<<<256, 256, 0, stream>>>(t, sums, N);
        k_bnfin<<<1, 128, 0, stream>>>(sums, bn1_g + L * 128, bn1_b + L * 128, bna, bnc, invN);
        k_bnapply<<<(N * 32 + 255) / 256, 256, 0, stream>>>(t, bna, bnc, x, N * 32);
        dim3 g2((N + 63) / 64, 512 / 64);
        k_gemm<true, true, false><<<g2, 256, 0, stream>>>(
            x, ff_w1 + (size_t)L * 128 * 512, ff_b1 + L * 512, nullptr, y, N, 512, 128);
        dim3 g3((N + 63) / 64, 128 / 64);
        k_gemm<false, false, true><<<g3, 256, 0, stream>>>(
            y, ff_w2 + (size_t)L * 512 * 128, nullptr, x, t, N, 128, 512);
        hipMemsetAsync(sums, 0, 256 * 4, stream);
        k_bnstats<<<256, 256, 0, stream>>>(t, sums, N);
        k_bnfin<<<1, 128, 0, stream>>>(sums, bn2_g + L * 128, bn2_b + L * 128, bna, bnc, invN);
        k_bnapply<<<(N * 32 + 255) / 256, 256, 0, stream>>>(t, bna, bnc, x, N * 32);
        cur = x;
    }
    k_cls<<<1024, 256, 0, stream>>>(x, cls_w, cls_b, (float*)d_out, N);
}

// Round 4
// 790.126 us; speedup vs baseline: 1.2991x; 1.2991x over previous
//
#include <hip/hip_runtime.h>
#include <stdint.h>

#define BN_EPS 1e-5f

typedef short short8 __attribute__((ext_vector_type(8)));
typedef float f32x4 __attribute__((ext_vector_type(4)));

__device__ __forceinline__ unsigned short f2bf(float f) {
    union { float f; unsigned int u; } v; v.f = f;
    unsigned int r = v.u + 0x7FFFu + ((v.u >> 16) & 1u);
    return (unsigned short)(r >> 16);
}

// ---------------- CSR build ----------------
__global__ void k_count(const int* __restrict__ dst, int* __restrict__ cnt, int E) {
    int i = blockIdx.x * 256 + threadIdx.x;
    if (i < E) atomicAdd(cnt + dst[i], 1);
}

__global__ void k_invdeg(const int* __restrict__ cnt, float* __restrict__ invd, int N) {
    int i = blockIdx.x * 256 + threadIdx.x;
    if (i < N) invd[i] = 1.0f / fmaxf((float)cnt[i], 1.0f);
}

__global__ void k_scan(const int* __restrict__ cnt, int* __restrict__ rowptr, int N) {
    __shared__ int part[1024];
    int t = threadIdx.x;
    int chunk = (N + 1023) >> 10;
    int lo = t * chunk, hi = min(lo + chunk, N);
    int s = 0;
    for (int i = lo; i < hi; ++i) s += cnt[i];
    part[t] = s;
    __syncthreads();
    for (int off = 1; off < 1024; off <<= 1) {
        int add = (t >= off) ? part[t - off] : 0;
        __syncthreads();
        part[t] += add;
        __syncthreads();
    }
    int run = part[t] - s;
    for (int i = lo; i < hi; ++i) { rowptr[i] = run; run += cnt[i]; }
    if (t == 1023) rowptr[N] = part[1023];
}

__global__ void k_fill(const int* __restrict__ src, const int* __restrict__ dst,
                       const int* __restrict__ rowptr, int* __restrict__ cursor,
                       int* __restrict__ srcs, int E) {
    int i = blockIdx.x * 256 + threadIdx.x;
    if (i < E) {
        int r = dst[i];
        int p = atomicAdd(cursor + r, 1);
        srcs[rowptr[r] + p] = src[i];
    }
}

// ---------------- weight convert+transpose to bf16 [Nn][K] ----------------
__global__ void k_convw(const float* __restrict__ Wg, const float* __restrict__ W1,
                        const float* __restrict__ W2, unsigned short* __restrict__ WgT,
                        unsigned short* __restrict__ W1T, unsigned short* __restrict__ W2T) {
    int id = blockIdx.x * 256 + threadIdx.x;
    if (id < 2 * 16384) {
        int L = id >> 14, e = id & 16383;
        int k = e >> 7, n = e & 127;
        WgT[(L << 14) + n * 128 + k] = f2bf(Wg[id]);
    } else if (id < 2 * 16384 + 2 * 65536) {
        int t = id - 2 * 16384;
        int L = t >> 16, e = t & 65535;
        int k = e >> 9, n = e & 511;
        W1T[(L << 16) + n * 128 + k] = f2bf(W1[t]);
    } else if (id < 2 * 16384 + 4 * 65536) {
        int t = id - 2 * 16384 - 2 * 65536;
        int L = t >> 16, e = t & 65535;
        int k = e >> 7, n = e & 127;
        W2T[(L << 16) + n * 512 + k] = f2bf(W2[t]);
    }
}

// ---------------- aggregation: one wave per dst node, bf16 out ----------------
__global__ __launch_bounds__(256) void k_agg(
    const float* __restrict__ x, const int* __restrict__ rowptr,
    const int* __restrict__ srcs, const float* __restrict__ invd,
    unsigned short* __restrict__ aggbf, int N) {
    int gw = (blockIdx.x * 256 + threadIdx.x) >> 6;
    int lane = threadIdx.x & 63;
    if (gw >= N) return;
    int lo = rowptr[gw], hi = rowptr[gw + 1];
    float ax = 0.f, ay = 0.f;
    const float2* x2 = (const float2*)x;
    for (int j = lo; j < hi; ++j) {
        int s = srcs[j];
        float2 v = x2[(size_t)s * 64 + lane];
        ax += v.x; ay += v.y;
    }
    float w = invd[gw];
    unsigned int pk = ((unsigned int)f2bf(ay * w) << 16) | (unsigned int)f2bf(ax * w);
    ((unsigned int*)aggbf)[(size_t)gw * 64 + lane] = pk;
}

// ---------------- bf16 MFMA GEMM: C = [relu](A @ BT^T [+bias] [+res]) ----------------
// A: [M_pad][K] bf16 row-major (padded, no load guards). BT: [Nn][K] bf16.
// 128x128 tile, BK=32, 256 threads = 4 waves (2x2 of 64x64).
template<bool RELU, bool HASB, bool RES, bool OUTBF>
__global__ __launch_bounds__(256) void k_mgemm(
    const unsigned short* __restrict__ A, const unsigned short* __restrict__ BT,
    const float* __restrict__ bias, const float* __restrict__ res,
    float* __restrict__ Cf, unsigned short* __restrict__ Cbf,
    int M, int Nn, int K) {
    __shared__ short As[128 * 32];
    __shared__ short Bs[128 * 32];
    int tid = threadIdx.x;
    int lane = tid & 63;
    int wid = tid >> 6;
    int wr = wid >> 1, wc = wid & 1;
    int row0 = blockIdx.x * 128, col0 = blockIdx.y * 128;
    int lm = lane & 15, hk = lane >> 4;

    // staging: thread -> (row sr, 8-elem slot ss); XOR swizzle slot by row for bank spread
    int sr = tid >> 2, ss = tid & 3;
    int wsw = sr * 32 + ((ss ^ ((sr >> 1) & 3)) << 3);
    const unsigned short* gA = A + (size_t)(row0 + sr) * K + ss * 8;
    const unsigned short* gB = BT + (size_t)(col0 + sr) * K + ss * 8;

    // fragment read offsets (loop-invariant), same swizzle
    int oA[4], oB[4];
#pragma unroll
    for (int i = 0; i < 4; ++i) {
        int ra = wr * 64 + i * 16 + lm;
        oA[i] = ra * 32 + ((hk ^ ((ra >> 1) & 3)) << 3);
        int rb = wc * 64 + i * 16 + lm;
        oB[i] = rb * 32 + ((hk ^ ((rb >> 1) & 3)) << 3);
    }

    f32x4 acc[4][4] = {};
    for (int k0 = 0; k0 < K; k0 += 32) {
        short8 va0 = *(const short8*)(gA + k0);
        short8 va1 = *(const short8*)(gA + (size_t)64 * K + k0);
        short8 vb0 = *(const short8*)(gB + k0);
        short8 vb1 = *(const short8*)(gB + (size_t)64 * K + k0);
        __syncthreads();
        *(short8*)&As[wsw] = va0;
        *(short8*)&As[wsw + 64 * 32] = va1;
        *(short8*)&Bs[wsw] = vb0;
        *(short8*)&Bs[wsw + 64 * 32] = vb1;
        __syncthreads();
        short8 a[4], b[4];
#pragma unroll
        for (int i = 0; i < 4; ++i) a[i] = *(const short8*)&As[oA[i]];
#pragma unroll
        for (int j = 0; j < 4; ++j) b[j] = *(const short8*)&Bs[oB[j]];
#pragma unroll
        for (int i = 0; i < 4; ++i)
#pragma unroll
            for (int j = 0; j < 4; ++j)
                acc[i][j] = __builtin_amdgcn_mfma_f32_16x16x32_bf16(a[i], b[j], acc[i][j], 0, 0, 0);
    }

#pragma unroll
    for (int j = 0; j < 4; ++j) {
        int col = col0 + wc * 64 + j * 16 + lm;
        float bj = 0.f;
        if (HASB) bj = bias[col];
#pragma unroll
        for (int i = 0; i < 4; ++i) {
#pragma unroll
            for (int r = 0; r < 4; ++r) {
                int row = row0 + wr * 64 + i * 16 + hk * 4 + r;
                if (row < M) {
                    float v = acc[i][j][r] + bj;
                    if (RES) v += res[(size_t)row * Nn + col];
                    if (RELU) v = fmaxf(v, 0.f);
                    if (OUTBF) Cbf[(size_t)row * Nn + col] = f2bf(v);
                    else Cf[(size_t)row * Nn + col] = v;
                }
            }
        }
    }
}

// ---------------- BatchNorm ----------------
__global__ __launch_bounds__(256) void k_bnstats(const float* __restrict__ t,
                                                 float* __restrict__ sums, int N) {
    __shared__ float ls[256];
    int tid = threadIdx.x;
    ls[tid] = 0.f;
    __syncthreads();
    int c4 = tid & 31, rg = tid >> 5;
    float4 s1 = make_float4(0.f, 0.f, 0.f, 0.f), s2 = make_float4(0.f, 0.f, 0.f, 0.f);
    for (int r = blockIdx.x * 8 + rg; r < N; r += gridDim.x * 8) {
        float4 v = ((const float4*)t)[(size_t)r * 32 + c4];
        s1.x += v.x; s1.y += v.y; s1.z += v.z; s1.w += v.w;
        s2.x += v.x * v.x; s2.y += v.y * v.y; s2.z += v.z * v.z; s2.w += v.w * v.w;
    }
    int c = c4 * 4;
    atomicAdd(&ls[c + 0], s1.x); atomicAdd(&ls[c + 1], s1.y);
    atomicAdd(&ls[c + 2], s1.z); atomicAdd(&ls[c + 3], s1.w);
    atomicAdd(&ls[128 + c + 0], s2.x); atomicAdd(&ls[128 + c + 1], s2.y);
    atomicAdd(&ls[128 + c + 2], s2.z); atomicAdd(&ls[128 + c + 3], s2.w);
    __syncthreads();
    atomicAdd(&sums[tid], ls[tid]);
}

// scale/shift from sums (recomputed per block), writes f32 + bf16 copies
__global__ __launch_bounds__(256) void k_bnapply(
    const float* __restrict__ t, const float* __restrict__ sums,
    const float* __restrict__ g, const float* __restrict__ b,
    float* __restrict__ xo, unsigned short* __restrict__ xbf,
    int N, float invN) {
    __shared__ float sa[128], sc[128];
    int tid = threadIdx.x;
    if (tid < 128) {
        float m = sums[tid] * invN;
        float var = sums[128 + tid] * invN - m * m;
        float a = g[tid] * rsqrtf(var + BN_EPS);
        sa[tid] = a; sc[tid] = b[tid] - m * a;
    }
    __syncthreads();
    int total4 = N * 32;
    for (int i = blockIdx.x * 256 + tid; i < total4; i += gridDim.x * 256) {
        int c4 = (i & 31) * 4;
        float4 v = ((const float4*)t)[i];
        float4 o;
        o.x = v.x * sa[c4 + 0] + sc[c4 + 0];
        o.y = v.y * sa[c4 + 1] + sc[c4 + 1];
        o.z = v.z * sa[c4 + 2] + sc[c4 + 2];
        o.w = v.w * sa[c4 + 3] + sc[c4 + 3];
        ((float4*)xo)[i] = o;
        uint2 pk;
        pk.x = ((unsigned)f2bf(o.y) << 16) | (unsigned)f2bf(o.x);
        pk.y = ((unsigned)f2bf(o.w) << 16) | (unsigned)f2bf(o.z);
        ((uint2*)xbf)[i] = pk;
    }
}

// ---------------- classifier ----------------
__global__ __launch_bounds__(256) void k_cls(const float* __restrict__ x,
                                             const float* __restrict__ w,
                                             const float* __restrict__ bias,
                                             float* __restrict__ out, int N) {
    int lane = threadIdx.x & 63;
    int wid = (blockIdx.x * blockDim.x + threadIdx.x) >> 6;
    int nw = (gridDim.x * blockDim.x) >> 6;
    float w0[16], w1[16];
#pragma unroll
    for (int c = 0; c < 16; ++c) {
        w0[c] = w[lane * 16 + c];
        w1[c] = w[(lane + 64) * 16 + c];
    }
    float bv = (lane < 16) ? bias[lane] : 0.f;
    for (int r = wid; r < N; r += nw) {
        float xv0 = x[(size_t)r * 128 + lane];
        float xv1 = x[(size_t)r * 128 + 64 + lane];
        float outv = 0.f;
#pragma unroll
        for (int c = 0; c < 16; ++c) {
            float p = xv0 * w0[c] + xv1 * w1[c];
            p += __shfl_xor(p, 1);  p += __shfl_xor(p, 2);
            p += __shfl_xor(p, 4);  p += __shfl_xor(p, 8);
            p += __shfl_xor(p, 16); p += __shfl_xor(p, 32);
            if (lane == c) outv = p;
        }
        if (lane < 16) out[(size_t)r * 16 + lane] = outv + bv;
    }
}

extern "C" void kernel_launch(void* const* d_in, const int* in_sizes, int n_in,
                              void* d_out, int out_size, void* d_ws, size_t ws_size,
                              hipStream_t stream) {
    const float* nodes = (const float*)d_in[0];
    const float* W_gcn = (const float*)d_in[1];
    const float* b_gcn = (const float*)d_in[2];
    const float* bn1_g = (const float*)d_in[3];
    const float* bn1_b = (const float*)d_in[4];
    const float* bn2_g = (const float*)d_in[5];
    const float* bn2_b = (const float*)d_in[6];
    const float* ff_w1 = (const float*)d_in[7];
    const float* ff_b1 = (const float*)d_in[8];
    const float* ff_w2 = (const float*)d_in[9];
    const float* cls_w = (const float*)d_in[10];
    const float* cls_b = (const float*)d_in[11];
    const int* esrc = (const int*)d_in[12];
    const int* edst = (const int*)d_in[13];
    const int N = in_sizes[0] / 128;
    const int E = in_sizes[12];
    const int M_pad = (N + 127) & ~127;

    char* p = (char*)d_ws;
    auto alloc = [&](size_t bytes) {
        void* r = (void*)p;
        p += (bytes + 255) & ~(size_t)255;
        return r;
    };
    // zero-region: cnt | cursor | 4x sums  (one memset)
    int* cnt      = (int*)alloc((size_t)N * 4);
    int* cursor   = (int*)alloc((size_t)N * 4);
    float* sums4  = (float*)alloc(4 * 256 * 4);
    size_t zbytes = (size_t)((char*)sums4 + 4 * 256 * 4 - (char*)cnt);

    float* x    = (float*)alloc((size_t)N * 128 * 4);
    float* t    = (float*)alloc((size_t)N * 128 * 4);
    float* invd = (float*)alloc((size_t)N * 4);
    int* rowptr = (int*)alloc((size_t)(N + 1) * 4);
    int* srcs   = (int*)alloc((size_t)E * 4);
    unsigned short* agg_bf = (unsigned short*)alloc((size_t)M_pad * 128 * 2);
    unsigned short* x_bf   = (unsigned short*)alloc((size_t)M_pad * 128 * 2);
    unsigned short* y_bf   = (unsigned short*)alloc((size_t)M_pad * 512 * 2);
    unsigned short* WgT = (unsigned short*)alloc(2 * 128 * 128 * 2);
    unsigned short* W1T = (unsigned short*)alloc(2 * 512 * 128 * 2);
    unsigned short* W2T = (unsigned short*)alloc(2 * 128 * 512 * 2);

    hipMemsetAsync(cnt, 0, zbytes, stream);
    k_count<<<(E + 255) / 256, 256, 0, stream>>>(edst, cnt, E);
    k_invdeg<<<(N + 255) / 256, 256, 0, stream>>>(cnt, invd, N);
    k_scan<<<1, 1024, 0, stream>>>(cnt, rowptr, N);
    k_fill<<<(E + 255) / 256, 256, 0, stream>>>(esrc, edst, rowptr, cursor, srcs, E);
    k_convw<<<1152, 256, 0, stream>>>(W_gcn, ff_w1, ff_w2, WgT, W1T, W2T);

    const float invN = 1.0f / (float)N;
    const int MB = M_pad / 128;
    const float* cur = nodes;
    for (int L = 0; L < 2; ++L) {
        k_agg<<<(N + 3) / 4, 256, 0, stream>>>(cur, rowptr, srcs, invd, agg_bf, N);
        k_mgemm<false, true, true, false><<<dim3(MB, 1), 256, 0, stream>>>(
            agg_bf, WgT + (size_t)L * 16384, b_gcn + L * 128, cur, t, nullptr, N, 128, 128);
        float* s1 = sums4 + (L * 2 + 0) * 256;
        k_bnstats<<<256, 256, 0, stream>>>(t, s1, N);
        k_bnapply<<<1600, 256, 0, stream>>>(t, s1, bn1_g + L * 128, bn1_b + L * 128,
                                            x, x_bf, N, invN);
        k_mgemm<true, true, false, true><<<dim3(MB, 4), 256, 0, stream>>>(
            x_bf, W1T + (size_t)L * 65536, ff_b1 + L * 512, nullptr, nullptr, y_bf, N, 512, 128);
        k_mgemm<false, false, true, false><<<dim3(MB, 1), 256, 0, stream>>>(
            y_bf, W2T + (size_t)L * 65536, nullptr, x, t, nullptr, N, 128, 512);
        float* s2 = sums4 + (L * 2 + 1) * 256;
        k_bnstats<<<256, 256, 0, stream>>>(t, s2, N);
        k_bnapply<<<1600, 256, 0, stream>>>(t, s2, bn2_g + L * 128, bn2_b + L * 128,
                                            x, x_bf, N, invN);
        cur = x;
    }
    k_cls<<<1024, 256, 0, stream>>>(x, cls_w, cls_b, (float*)d_out, N);
}

// Round 5
// 690.886 us; speedup vs baseline: 1.4856x; 1.1436x over previous
//
#include <hip/hip_runtime.h>
#include <stdint.h>

#define BN_EPS 1e-5f

typedef short short8 __attribute__((ext_vector_type(8)));
typedef float f32x4 __attribute__((ext_vector_type(4)));

__device__ __forceinline__ unsigned short f2bf(float f) {
    union { float f; unsigned int u; } v; v.f = f;
    unsigned int r = v.u + 0x7FFFu + ((v.u >> 16) & 1u);
    return (unsigned short)(r >> 16);
}
__device__ __forceinline__ float bf2f(unsigned short h) {
    union { unsigned int u; float f; } v; v.u = (unsigned int)h << 16; return v.f;
}

// ---------------- CSR build ----------------
__global__ void k_count(const int* __restrict__ dst, int* __restrict__ cnt, int E) {
    int i = blockIdx.x * 256 + threadIdx.x;
    if (i < E) atomicAdd(cnt + dst[i], 1);
}

__global__ void k_scan(const int* __restrict__ cnt, int* __restrict__ rowptr, int N) {
    __shared__ int part[1024];
    int t = threadIdx.x;
    int chunk = (N + 1023) >> 10;
    int lo = t * chunk, hi = min(lo + chunk, N);
    int s = 0;
    for (int i = lo; i < hi; ++i) s += cnt[i];
    part[t] = s;
    __syncthreads();
    for (int off = 1; off < 1024; off <<= 1) {
        int add = (t >= off) ? part[t - off] : 0;
        __syncthreads();
        part[t] += add;
        __syncthreads();
    }
    int run = part[t] - s;
    for (int i = lo; i < hi; ++i) { rowptr[i] = run; run += cnt[i]; }
    if (t == 1023) rowptr[N] = part[1023];
}

__global__ void k_fill(const int* __restrict__ src, const int* __restrict__ dst,
                       const int* __restrict__ rowptr, int* __restrict__ cursor,
                       int* __restrict__ srcs, int E) {
    int i = blockIdx.x * 256 + threadIdx.x;
    if (i < E) {
        int r = dst[i];
        int p = atomicAdd(cursor + r, 1);
        srcs[rowptr[r] + p] = src[i];
    }
}

// ---------------- weight convert+transpose to bf16 [Nn][K] (+ cls_w) ----------------
__global__ void k_convw(const float* __restrict__ Wg, const float* __restrict__ W1,
                        const float* __restrict__ W2, const float* __restrict__ Wc,
                        unsigned short* __restrict__ WgT, unsigned short* __restrict__ W1T,
                        unsigned short* __restrict__ W2T, unsigned short* __restrict__ WcT) {
    int id = blockIdx.x * 256 + threadIdx.x;
    if (id < 2 * 16384) {
        int L = id >> 14, e = id & 16383;
        int k = e >> 7, n = e & 127;
        WgT[(L << 14) + n * 128 + k] = f2bf(Wg[id]);
    } else if (id < 2 * 16384 + 2 * 65536) {
        int t = id - 2 * 16384;
        int L = t >> 16, e = t & 65535;
        int k = e >> 9, n = e & 511;
        W1T[(L << 16) + n * 128 + k] = f2bf(W1[t]);
    } else if (id < 2 * 16384 + 4 * 65536) {
        int t = id - 2 * 16384 - 2 * 65536;
        int L = t >> 16, e = t & 65535;
        int k = e >> 7, n = e & 127;
        W2T[(L << 16) + n * 512 + k] = f2bf(W2[t]);
    } else if (id < 2 * 16384 + 4 * 65536 + 2048) {
        int t = id - 2 * 16384 - 4 * 65536;
        int k = t >> 4, c = t & 15;
        WcT[c * 128 + k] = f2bf(Wc[t]);
    }
}

// nodes f32 -> bf16 (packed)
__global__ void k_convn(const float* __restrict__ nf, unsigned short* __restrict__ nbf, int n2) {
    for (int i = blockIdx.x * 256 + threadIdx.x; i < n2; i += gridDim.x * 256) {
        float2 v = ((const float2*)nf)[i];
        ((unsigned int*)nbf)[i] = ((unsigned int)f2bf(v.y) << 16) | (unsigned int)f2bf(v.x);
    }
}

// ---------------- aggregation: one wave per dst node, bf16 in/out ----------------
__global__ __launch_bounds__(256) void k_agg(
    const unsigned short* __restrict__ xbf, const int* __restrict__ rowptr,
    const int* __restrict__ srcs, unsigned short* __restrict__ aggbf, int N) {
    int gw = (blockIdx.x * 256 + threadIdx.x) >> 6;
    int lane = threadIdx.x & 63;
    if (gw >= N) return;
    int lo = rowptr[gw], hi = rowptr[gw + 1];
    float ax = 0.f, ay = 0.f;
    const unsigned int* x1 = (const unsigned int*)xbf;
    for (int j = lo; j < hi; ++j) {
        int s = srcs[j];
        unsigned int pk = x1[(size_t)s * 64 + lane];
        ax += bf2f((unsigned short)pk);
        ay += bf2f((unsigned short)(pk >> 16));
    }
    float w = 1.0f / fmaxf((float)(hi - lo), 1.0f);
    ((unsigned int*)aggbf)[(size_t)gw * 64 + lane] =
        ((unsigned int)f2bf(ay * w) << 16) | (unsigned int)f2bf(ax * w);
}

// ---------------- bf16 MFMA GEMM: C = [relu](A @ BT^T [+bias] [+res_bf16]) [+BN stats] ----
// A: [M_pad][K] bf16 row-major. BT: [Nn][K] bf16. 128x128 tile, BK=32, 4 waves.
template<bool RELU, bool HASB, bool RES, bool OUTBF, bool STATS>
__global__ __launch_bounds__(256) void k_mgemm(
    const unsigned short* __restrict__ A, const unsigned short* __restrict__ BT,
    const float* __restrict__ bias, const unsigned short* __restrict__ res,
    float* __restrict__ Cf, unsigned short* __restrict__ Cbf,
    float* __restrict__ sums, int M, int Nn, int K) {
    __shared__ short As[128 * 32];
    __shared__ short Bs[128 * 32];
    int tid = threadIdx.x;
    int lane = tid & 63;
    int wid = tid >> 6;
    int wr = wid >> 1, wc = wid & 1;
    int row0 = blockIdx.x * 128, col0 = blockIdx.y * 128;
    int lm = lane & 15, hk = lane >> 4;

    int sr = tid >> 2, ss = tid & 3;
    int wsw = sr * 32 + ((ss ^ ((sr >> 1) & 3)) << 3);
    const unsigned short* gA = A + (size_t)(row0 + sr) * K + ss * 8;
    const unsigned short* gB = BT + (size_t)(col0 + sr) * K + ss * 8;

    int oA[4], oB[4];
#pragma unroll
    for (int i = 0; i < 4; ++i) {
        int ra = wr * 64 + i * 16 + lm;
        oA[i] = ra * 32 + ((hk ^ ((ra >> 1) & 3)) << 3);
        int rb = wc * 64 + i * 16 + lm;
        oB[i] = rb * 32 + ((hk ^ ((rb >> 1) & 3)) << 3);
    }

    f32x4 acc[4][4] = {};
    for (int k0 = 0; k0 < K; k0 += 32) {
        short8 va0 = *(const short8*)(gA + k0);
        short8 va1 = *(const short8*)(gA + (size_t)64 * K + k0);
        short8 vb0 = *(const short8*)(gB + k0);
        short8 vb1 = *(const short8*)(gB + (size_t)64 * K + k0);
        __syncthreads();
        *(short8*)&As[wsw] = va0;
        *(short8*)&As[wsw + 64 * 32] = va1;
        *(short8*)&Bs[wsw] = vb0;
        *(short8*)&Bs[wsw + 64 * 32] = vb1;
        __syncthreads();
        short8 a[4], b[4];
#pragma unroll
        for (int i = 0; i < 4; ++i) a[i] = *(const short8*)&As[oA[i]];
#pragma unroll
        for (int j = 0; j < 4; ++j) b[j] = *(const short8*)&Bs[oB[j]];
#pragma unroll
        for (int i = 0; i < 4; ++i)
#pragma unroll
            for (int j = 0; j < 4; ++j)
                acc[i][j] = __builtin_amdgcn_mfma_f32_16x16x32_bf16(a[i], b[j], acc[i][j], 0, 0, 0);
    }

    float th_s[4] = {0.f, 0.f, 0.f, 0.f}, th_q[4] = {0.f, 0.f, 0.f, 0.f};
#pragma unroll
    for (int j = 0; j < 4; ++j) {
        int col = col0 + wc * 64 + j * 16 + lm;
        float bj = 0.f;
        if (HASB) bj = bias[col];
#pragma unroll
        for (int i = 0; i < 4; ++i) {
#pragma unroll
            for (int r = 0; r < 4; ++r) {
                int row = row0 + wr * 64 + i * 16 + hk * 4 + r;
                if (row < M) {
                    float v = acc[i][j][r] + bj;
                    if (RES) v += bf2f(res[(size_t)row * Nn + col]);
                    if (RELU) v = fmaxf(v, 0.f);
                    if (STATS) { th_s[j] += v; th_q[j] += v * v; }
                    if (OUTBF) Cbf[(size_t)row * Nn + col] = f2bf(v);
                    else Cf[(size_t)row * Nn + col] = v;
                }
            }
        }
    }
    if (STATS) {
#pragma unroll
        for (int j = 0; j < 4; ++j) {
            float s = th_s[j], q = th_q[j];
            s += __shfl_xor(s, 16); s += __shfl_xor(s, 32);
            q += __shfl_xor(q, 16); q += __shfl_xor(q, 32);
            if (hk == 0) {
                int col = col0 + wc * 64 + j * 16 + lm;
                atomicAdd(&sums[col], s);
                atomicAdd(&sums[128 + col], q);
            }
        }
    }
}

// ---------------- BN apply: x_bf = bf16((t - m) * a + b) ----------------
__global__ __launch_bounds__(256) void k_bnapply(
    const float* __restrict__ t, const float* __restrict__ sums,
    const float* __restrict__ g, const float* __restrict__ b,
    unsigned short* __restrict__ xbf, int N, float invN) {
    __shared__ float sa[128], sc[128];
    int tid = threadIdx.x;
    if (tid < 128) {
        float m = sums[tid] * invN;
        float var = sums[128 + tid] * invN - m * m;
        float a = g[tid] * rsqrtf(var + BN_EPS);
        sa[tid] = a; sc[tid] = b[tid] - m * a;
    }
    __syncthreads();
    int total4 = N * 32;
    for (int i = blockIdx.x * 256 + tid; i < total4; i += gridDim.x * 256) {
        int c4 = (i & 31) * 4;
        float4 v = ((const float4*)t)[i];
        float ox = v.x * sa[c4 + 0] + sc[c4 + 0];
        float oy = v.y * sa[c4 + 1] + sc[c4 + 1];
        float oz = v.z * sa[c4 + 2] + sc[c4 + 2];
        float ow = v.w * sa[c4 + 3] + sc[c4 + 3];
        uint2 pk;
        pk.x = ((unsigned)f2bf(oy) << 16) | (unsigned)f2bf(ox);
        pk.y = ((unsigned)f2bf(ow) << 16) | (unsigned)f2bf(oz);
        ((uint2*)xbf)[i] = pk;
    }
}

// ---------------- classifier: MFMA, one wave per 16-row tile ----------------
__global__ __launch_bounds__(256) void k_cls(
    const unsigned short* __restrict__ xbf, const unsigned short* __restrict__ wT,
    const float* __restrict__ bias, float* __restrict__ out, int N) {
    int wv = (blockIdx.x * 256 + threadIdx.x) >> 6;
    int lane = threadIdx.x & 63;
    int lm = lane & 15, hk = lane >> 4;
    int r0 = wv * 16;
    f32x4 acc = {};
    const unsigned short* xr = xbf + (size_t)(r0 + lm) * 128 + hk * 8;
    const unsigned short* wr = wT + lm * 128 + hk * 8;
#pragma unroll
    for (int ks = 0; ks < 4; ++ks) {
        short8 a = *(const short8*)(xr + ks * 32);
        short8 b = *(const short8*)(wr + ks * 32);
        acc = __builtin_amdgcn_mfma_f32_16x16x32_bf16(a, b, acc, 0, 0, 0);
    }
    float bv = bias[lm];
#pragma unroll
    for (int r = 0; r < 4; ++r) {
        int row = r0 + hk * 4 + r;
        if (row < N) out[(size_t)row * 16 + lm] = acc[r] + bv;
    }
}

extern "C" void kernel_launch(void* const* d_in, const int* in_sizes, int n_in,
                              void* d_out, int out_size, void* d_ws, size_t ws_size,
                              hipStream_t stream) {
    const float* nodes = (const float*)d_in[0];
    const float* W_gcn = (const float*)d_in[1];
    const float* b_gcn = (const float*)d_in[2];
    const float* bn1_g = (const float*)d_in[3];
    const float* bn1_b = (const float*)d_in[4];
    const float* bn2_g = (const float*)d_in[5];
    const float* bn2_b = (const float*)d_in[6];
    const float* ff_w1 = (const float*)d_in[7];
    const float* ff_b1 = (const float*)d_in[8];
    const float* ff_w2 = (const float*)d_in[9];
    const float* cls_w = (const float*)d_in[10];
    const float* cls_b = (const float*)d_in[11];
    const int* esrc = (const int*)d_in[12];
    const int* edst = (const int*)d_in[13];
    const int N = in_sizes[0] / 128;
    const int E = in_sizes[12];
    const int M_pad = (N + 127) & ~127;

    char* p = (char*)d_ws;
    auto alloc = [&](size_t bytes) {
        void* r = (void*)p;
        p += (bytes + 255) & ~(size_t)255;
        return r;
    };
    // zero-region: cnt | cursor | 4x sums  (one memset)
    int* cnt      = (int*)alloc((size_t)N * 4);
    int* cursor   = (int*)alloc((size_t)N * 4);
    float* sums4  = (float*)alloc(4 * 256 * 4);
    size_t zbytes = (size_t)((char*)sums4 + 4 * 256 * 4 - (char*)cnt);

    float* t    = (float*)alloc((size_t)N * 128 * 4);
    int* rowptr = (int*)alloc((size_t)(N + 1) * 4);
    int* srcs   = (int*)alloc((size_t)E * 4);
    unsigned short* nodes_bf = (unsigned short*)alloc((size_t)M_pad * 128 * 2);
    unsigned short* agg_bf   = (unsigned short*)alloc((size_t)M_pad * 128 * 2);
    unsigned short* x_bf     = (unsigned short*)alloc((size_t)M_pad * 128 * 2);
    unsigned short* y_bf     = (unsigned short*)alloc((size_t)M_pad * 512 * 2);
    unsigned short* WgT = (unsigned short*)alloc(2 * 128 * 128 * 2);
    unsigned short* W1T = (unsigned short*)alloc(2 * 512 * 128 * 2);
    unsigned short* W2T = (unsigned short*)alloc(2 * 128 * 512 * 2);
    unsigned short* WcT = (unsigned short*)alloc(16 * 128 * 2);

    hipMemsetAsync(cnt, 0, zbytes, stream);
    k_count<<<(E + 255) / 256, 256, 0, stream>>>(edst, cnt, E);
    k_scan<<<1, 1024, 0, stream>>>(cnt, rowptr, N);
    k_fill<<<(E + 255) / 256, 256, 0, stream>>>(esrc, edst, rowptr, cursor, srcs, E);
    k_convw<<<1160, 256, 0, stream>>>(W_gcn, ff_w1, ff_w2, cls_w, WgT, W1T, W2T, WcT);
    k_convn<<<1600, 256, 0, stream>>>(nodes, nodes_bf, N * 64);

    const float invN = 1.0f / (float)N;
    const int MB = M_pad / 128;
    const unsigned short* cur_bf = nodes_bf;
    for (int L = 0; L < 2; ++L) {
        k_agg<<<(N + 3) / 4, 256, 0, stream>>>(cur_bf, rowptr, srcs, agg_bf, N);
        float* s1 = sums4 + (L * 2 + 0) * 256;
        // GCN: t = agg@Wg + b + res(cur_bf), f32 out, fused BN1 stats
        k_mgemm<false, true, true, false, true><<<dim3(MB, 1), 256, 0, stream>>>(
            agg_bf, WgT + (size_t)L * 16384, b_gcn + L * 128, cur_bf, t, nullptr, s1,
            N, 128, 128);
        k_bnapply<<<1600, 256, 0, stream>>>(t, s1, bn1_g + L * 128, bn1_b + L * 128,
                                            x_bf, N, invN);
        // FF1: y = relu(x@W1 + b1), bf16 out
        k_mgemm<true, true, false, true, false><<<dim3(MB, 4), 256, 0, stream>>>(
            x_bf, W1T + (size_t)L * 65536, ff_b1 + L * 512, nullptr, nullptr, y_bf, nullptr,
            N, 512, 128);
        float* s2 = sums4 + (L * 2 + 1) * 256;
        // FF2: t = y@W2 + res(x_bf), f32 out, fused BN2 stats
        k_mgemm<false, false, true, false, true><<<dim3(MB, 1), 256, 0, stream>>>(
            y_bf, W2T + (size_t)L * 65536, nullptr, x_bf, t, nullptr, s2,
            N, 128, 512);
        k_bnapply<<<1600, 256, 0, stream>>>(t, s2, bn2_g + L * 128, bn2_b + L * 128,
                                            x_bf, N, invN);
        cur_bf = x_bf;
    }
    k_cls<<<(M_pad / 16 + 3) / 4, 256, 0, stream>>>(x_bf, WcT, cls_b, (float*)d_out, N);
}

// Round 6
// 544.134 us; speedup vs baseline: 1.8863x; 1.2697x over previous
//
#include <hip/hip_runtime.h>
#include <stdint.h>

#define BN_EPS 1e-5f
#define SCAN_G 128

typedef short short8 __attribute__((ext_vector_type(8)));
typedef float f32x4 __attribute__((ext_vector_type(4)));

__device__ __forceinline__ unsigned short f2bf(float f) {
    union { float f; unsigned int u; } v; v.f = f;
    unsigned int r = v.u + 0x7FFFu + ((v.u >> 16) & 1u);
    return (unsigned short)(r >> 16);
}
__device__ __forceinline__ float bf2f(unsigned short h) {
    union { unsigned int u; float f; } v; v.u = (unsigned int)h << 16; return v.f;
}

// ---------------- CSR build ----------------
__global__ void k_count(const int* __restrict__ dst, int* __restrict__ cnt, int E) {
    int i = blockIdx.x * 256 + threadIdx.x;
    if (i < E) atomicAdd(cnt + dst[i], 1);
}

// parallel 3-stage exclusive scan of cnt[0..N-1] -> rowptr[0..N]
__global__ __launch_bounds__(256) void k_scanA(const int* __restrict__ cnt,
                                               int* __restrict__ bsum, int N) {
    __shared__ int red[256];
    int b = blockIdx.x, t = threadIdx.x;
    int C = (N + SCAN_G - 1) / SCAN_G;
    int c = (C + 255) >> 8;
    int lo = b * C + t * c;
    int hi = min(lo + c, min((b + 1) * C, N));
    int s = 0;
    for (int i = lo; i < hi; ++i) s += cnt[i];
    red[t] = s;
    __syncthreads();
    for (int off = 128; off > 0; off >>= 1) {
        if (t < off) red[t] += red[t + off];
        __syncthreads();
    }
    if (t == 0) bsum[b] = red[0];
}
__global__ void k_scanB(const int* __restrict__ bsum, int* __restrict__ boff,
                        int* __restrict__ rowptr, int N) {
    __shared__ int sh[SCAN_G];
    int t = threadIdx.x;
    int v = bsum[t];
    sh[t] = v;
    __syncthreads();
    for (int off = 1; off < SCAN_G; off <<= 1) {
        int add = (t >= off) ? sh[t - off] : 0;
        __syncthreads();
        sh[t] += add;
        __syncthreads();
    }
    boff[t] = sh[t] - v;
    if (t == SCAN_G - 1) rowptr[N] = sh[t];
}
__global__ __launch_bounds__(256) void k_scanC(const int* __restrict__ cnt,
                                               const int* __restrict__ boff,
                                               int* __restrict__ rowptr, int N) {
    __shared__ int sh[256];
    int b = blockIdx.x, t = threadIdx.x;
    int C = (N + SCAN_G - 1) / SCAN_G;
    int c = (C + 255) >> 8;
    int lo = b * C + t * c;
    int hi = min(lo + c, min((b + 1) * C, N));
    int s = 0;
    for (int i = lo; i < hi; ++i) s += cnt[i];
    sh[t] = s;
    __syncthreads();
    for (int off = 1; off < 256; off <<= 1) {
        int add = (t >= off) ? sh[t - off] : 0;
        __syncthreads();
        sh[t] += add;
        __syncthreads();
    }
    int run = boff[b] + sh[t] - s;
    for (int i = lo; i < hi; ++i) { rowptr[i] = run; run += cnt[i]; }
}

__global__ void k_fill(const int* __restrict__ src, const int* __restrict__ dst,
                       const int* __restrict__ rowptr, int* __restrict__ cursor,
                       int* __restrict__ srcs, int E) {
    int i = blockIdx.x * 256 + threadIdx.x;
    if (i < E) {
        int r = dst[i];
        int p = atomicAdd(cursor + r, 1);
        srcs[rowptr[r] + p] = src[i];
    }
}

// ---------------- weight convert+transpose to bf16 [Nn][K] (+ cls_w) ----------------
__global__ void k_convw(const float* __restrict__ Wg, const float* __restrict__ W1,
                        const float* __restrict__ W2, const float* __restrict__ Wc,
                        unsigned short* __restrict__ WgT, unsigned short* __restrict__ W1T,
                        unsigned short* __restrict__ W2T, unsigned short* __restrict__ WcT) {
    int id = blockIdx.x * 256 + threadIdx.x;
    if (id < 2 * 16384) {
        int L = id >> 14, e = id & 16383;
        int k = e >> 7, n = e & 127;
        WgT[(L << 14) + n * 128 + k] = f2bf(Wg[id]);
    } else if (id < 2 * 16384 + 2 * 65536) {
        int t = id - 2 * 16384;
        int L = t >> 16, e = t & 65535;
        int k = e >> 9, n = e & 511;
        W1T[(L << 16) + n * 128 + k] = f2bf(W1[t]);
    } else if (id < 2 * 16384 + 4 * 65536) {
        int t = id - 2 * 16384 - 2 * 65536;
        int L = t >> 16, e = t & 65535;
        int k = e >> 7, n = e & 127;
        W2T[(L << 16) + n * 512 + k] = f2bf(W2[t]);
    } else if (id < 2 * 16384 + 4 * 65536 + 2048) {
        int t = id - 2 * 16384 - 4 * 65536;
        int k = t >> 4, c = t & 15;
        WcT[c * 128 + k] = f2bf(Wc[t]);
    }
}

// nodes f32 -> bf16 (packed)
__global__ void k_convn(const float* __restrict__ nf, unsigned short* __restrict__ nbf, int n2) {
    for (int i = blockIdx.x * 256 + threadIdx.x; i < n2; i += gridDim.x * 256) {
        float2 v = ((const float2*)nf)[i];
        ((unsigned int*)nbf)[i] = ((unsigned int)f2bf(v.y) << 16) | (unsigned int)f2bf(v.x);
    }
}

// ---------------- aggregation: one wave per dst node, bf16 in/out, 4x unroll ----------------
__global__ __launch_bounds__(256) void k_agg(
    const unsigned short* __restrict__ xbf, const int* __restrict__ rowptr,
    const int* __restrict__ srcs, unsigned short* __restrict__ aggbf, int N) {
    int gw = (blockIdx.x * 256 + threadIdx.x) >> 6;
    int lane = threadIdx.x & 63;
    if (gw >= N) return;
    int lo = rowptr[gw], hi = rowptr[gw + 1];
    float ax = 0.f, ay = 0.f;
    const unsigned int* x1 = (const unsigned int*)xbf;
    int j = lo;
    for (; j + 4 <= hi; j += 4) {
        int s0 = srcs[j], s1 = srcs[j + 1], s2 = srcs[j + 2], s3 = srcs[j + 3];
        unsigned int p0 = x1[(size_t)s0 * 64 + lane];
        unsigned int p1 = x1[(size_t)s1 * 64 + lane];
        unsigned int p2 = x1[(size_t)s2 * 64 + lane];
        unsigned int p3 = x1[(size_t)s3 * 64 + lane];
        ax += bf2f((unsigned short)p0) + bf2f((unsigned short)p1)
            + bf2f((unsigned short)p2) + bf2f((unsigned short)p3);
        ay += bf2f((unsigned short)(p0 >> 16)) + bf2f((unsigned short)(p1 >> 16))
            + bf2f((unsigned short)(p2 >> 16)) + bf2f((unsigned short)(p3 >> 16));
    }
    for (; j < hi; ++j) {
        unsigned int pk = x1[(size_t)srcs[j] * 64 + lane];
        ax += bf2f((unsigned short)pk);
        ay += bf2f((unsigned short)(pk >> 16));
    }
    float w = 1.0f / fmaxf((float)(hi - lo), 1.0f);
    ((unsigned int*)aggbf)[(size_t)gw * 64 + lane] =
        ((unsigned int)f2bf(ay * w) << 16) | (unsigned int)f2bf(ax * w);
}

// ---------------- bf16 MFMA GEMM: C = [relu](A @ BT^T [+bias] [+res_bf16]) [+BN stats] ----
template<bool RELU, bool HASB, bool RES, bool OUTBF, bool STATS>
__global__ __launch_bounds__(256) void k_mgemm(
    const unsigned short* __restrict__ A, const unsigned short* __restrict__ BT,
    const float* __restrict__ bias, const unsigned short* __restrict__ res,
    float* __restrict__ Cf, unsigned short* __restrict__ Cbf,
    float* __restrict__ sums, int M, int Nn, int K) {
    __shared__ short As[128 * 32];
    __shared__ short Bs[128 * 32];
    int tid = threadIdx.x;
    int lane = tid & 63;
    int wid = tid >> 6;
    int wr = wid >> 1, wc = wid & 1;
    int row0 = blockIdx.x * 128, col0 = blockIdx.y * 128;
    int lm = lane & 15, hk = lane >> 4;

    int sr = tid >> 2, ss = tid & 3;
    int wsw = sr * 32 + ((ss ^ ((sr >> 1) & 3)) << 3);
    const unsigned short* gA = A + (size_t)(row0 + sr) * K + ss * 8;
    const unsigned short* gB = BT + (size_t)(col0 + sr) * K + ss * 8;

    int oA[4], oB[4];
#pragma unroll
    for (int i = 0; i < 4; ++i) {
        int ra = wr * 64 + i * 16 + lm;
        oA[i] = ra * 32 + ((hk ^ ((ra >> 1) & 3)) << 3);
        int rb = wc * 64 + i * 16 + lm;
        oB[i] = rb * 32 + ((hk ^ ((rb >> 1) & 3)) << 3);
    }

    f32x4 acc[4][4] = {};
    for (int k0 = 0; k0 < K; k0 += 32) {
        short8 va0 = *(const short8*)(gA + k0);
        short8 va1 = *(const short8*)(gA + (size_t)64 * K + k0);
        short8 vb0 = *(const short8*)(gB + k0);
        short8 vb1 = *(const short8*)(gB + (size_t)64 * K + k0);
        __syncthreads();
        *(short8*)&As[wsw] = va0;
        *(short8*)&As[wsw + 64 * 32] = va1;
        *(short8*)&Bs[wsw] = vb0;
        *(short8*)&Bs[wsw + 64 * 32] = vb1;
        __syncthreads();
        short8 a[4], b[4];
#pragma unroll
        for (int i = 0; i < 4; ++i) a[i] = *(const short8*)&As[oA[i]];
#pragma unroll
        for (int j = 0; j < 4; ++j) b[j] = *(const short8*)&Bs[oB[j]];
#pragma unroll
        for (int i = 0; i < 4; ++i)
#pragma unroll
            for (int j = 0; j < 4; ++j)
                acc[i][j] = __builtin_amdgcn_mfma_f32_16x16x32_bf16(a[i], b[j], acc[i][j], 0, 0, 0);
    }

    float th_s[4] = {0.f, 0.f, 0.f, 0.f}, th_q[4] = {0.f, 0.f, 0.f, 0.f};
#pragma unroll
    for (int j = 0; j < 4; ++j) {
        int col = col0 + wc * 64 + j * 16 + lm;
        float bj = 0.f;
        if (HASB) bj = bias[col];
#pragma unroll
        for (int i = 0; i < 4; ++i) {
#pragma unroll
            for (int r = 0; r < 4; ++r) {
                int row = row0 + wr * 64 + i * 16 + hk * 4 + r;
                if (row < M) {
                    float v = acc[i][j][r] + bj;
                    if (RES) v += bf2f(res[(size_t)row * Nn + col]);
                    if (RELU) v = fmaxf(v, 0.f);
                    if (STATS) { th_s[j] += v; th_q[j] += v * v; }
                    if (OUTBF) Cbf[(size_t)row * Nn + col] = f2bf(v);
                    else Cf[(size_t)row * Nn + col] = v;
                }
            }
        }
    }
    if (STATS) {
#pragma unroll
        for (int j = 0; j < 4; ++j) {
            float s = th_s[j], q = th_q[j];
            s += __shfl_xor(s, 16); s += __shfl_xor(s, 32);
            q += __shfl_xor(q, 16); q += __shfl_xor(q, 32);
            if (hk == 0) {
                int col = col0 + wc * 64 + j * 16 + lm;
                atomicAdd(&sums[col], s);
                atomicAdd(&sums[128 + col], q);
            }
        }
    }
}

// ---------------- BN apply: x_bf = bf16((t - m) * a + b) ----------------
__global__ __launch_bounds__(256) void k_bnapply(
    const float* __restrict__ t, const float* __restrict__ sums,
    const float* __restrict__ g, const float* __restrict__ b,
    unsigned short* __restrict__ xbf, int N, float invN) {
    __shared__ float sa[128], sc[128];
    int tid = threadIdx.x;
    if (tid < 128) {
        float m = sums[tid] * invN;
        float var = sums[128 + tid] * invN - m * m;
        float a = g[tid] * rsqrtf(var + BN_EPS);
        sa[tid] = a; sc[tid] = b[tid] - m * a;
    }
    __syncthreads();
    int total4 = N * 32;
    for (int i = blockIdx.x * 256 + tid; i < total4; i += gridDim.x * 256) {
        int c4 = (i & 31) * 4;
        float4 v = ((const float4*)t)[i];
        float ox = v.x * sa[c4 + 0] + sc[c4 + 0];
        float oy = v.y * sa[c4 + 1] + sc[c4 + 1];
        float oz = v.z * sa[c4 + 2] + sc[c4 + 2];
        float ow = v.w * sa[c4 + 3] + sc[c4 + 3];
        uint2 pk;
        pk.x = ((unsigned)f2bf(oy) << 16) | (unsigned)f2bf(ox);
        pk.y = ((unsigned)f2bf(ow) << 16) | (unsigned)f2bf(oz);
        ((uint2*)xbf)[i] = pk;
    }
}

// ---------------- classifier: MFMA, one wave per 16-row tile ----------------
__global__ __launch_bounds__(256) void k_cls(
    const unsigned short* __restrict__ xbf, const unsigned short* __restrict__ wT,
    const float* __restrict__ bias, float* __restrict__ out, int N) {
    int wv = (blockIdx.x * 256 + threadIdx.x) >> 6;
    int lane = threadIdx.x & 63;
    int lm = lane & 15, hk = lane >> 4;
    int r0 = wv * 16;
    f32x4 acc = {};
    const unsigned short* xr = xbf + (size_t)(r0 + lm) * 128 + hk * 8;
    const unsigned short* wr = wT + lm * 128 + hk * 8;
#pragma unroll
    for (int ks = 0; ks < 4; ++ks) {
        short8 a = *(const short8*)(xr + ks * 32);
        short8 b = *(const short8*)(wr + ks * 32);
        acc = __builtin_amdgcn_mfma_f32_16x16x32_bf16(a, b, acc, 0, 0, 0);
    }
    float bv = bias[lm];
#pragma unroll
    for (int r = 0; r < 4; ++r) {
        int row = r0 + hk * 4 + r;
        if (row < N) out[(size_t)row * 16 + lm] = acc[r] + bv;
    }
}

extern "C" void kernel_launch(void* const* d_in, const int* in_sizes, int n_in,
                              void* d_out, int out_size, void* d_ws, size_t ws_size,
                              hipStream_t stream) {
    const float* nodes = (const float*)d_in[0];
    const float* W_gcn = (const float*)d_in[1];
    const float* b_gcn = (const float*)d_in[2];
    const float* bn1_g = (const float*)d_in[3];
    const float* bn1_b = (const float*)d_in[4];
    const float* bn2_g = (const float*)d_in[5];
    const float* bn2_b = (const float*)d_in[6];
    const float* ff_w1 = (const float*)d_in[7];
    const float* ff_b1 = (const float*)d_in[8];
    const float* ff_w2 = (const float*)d_in[9];
    const float* cls_w = (const float*)d_in[10];
    const float* cls_b = (const float*)d_in[11];
    const int* esrc = (const int*)d_in[12];
    const int* edst = (const int*)d_in[13];
    const int N = in_sizes[0] / 128;
    const int E = in_sizes[12];
    const int M_pad = (N + 127) & ~127;

    char* p = (char*)d_ws;
    auto alloc = [&](size_t bytes) {
        void* r = (void*)p;
        p += (bytes + 255) & ~(size_t)255;
        return r;
    };
    // zero-region: cnt | cursor | 4x sums  (one memset)
    int* cnt      = (int*)alloc((size_t)N * 4);
    int* cursor   = (int*)alloc((size_t)N * 4);
    float* sums4  = (float*)alloc(4 * 256 * 4);
    size_t zbytes = (size_t)((char*)sums4 + 4 * 256 * 4 - (char*)cnt);

    float* t    = (float*)alloc((size_t)N * 128 * 4);
    int* rowptr = (int*)alloc((size_t)(N + 1) * 4);
    int* srcs   = (int*)alloc((size_t)E * 4);
    int* bsum   = (int*)alloc(SCAN_G * 4);
    int* boff   = (int*)alloc(SCAN_G * 4);
    unsigned short* nodes_bf = (unsigned short*)alloc((size_t)M_pad * 128 * 2);
    unsigned short* agg_bf   = (unsigned short*)alloc((size_t)M_pad * 128 * 2);
    unsigned short* x_bf     = (unsigned short*)alloc((size_t)M_pad * 128 * 2);
    unsigned short* y_bf     = (unsigned short*)alloc((size_t)M_pad * 512 * 2);
    unsigned short* WgT = (unsigned short*)alloc(2 * 128 * 128 * 2);
    unsigned short* W1T = (unsigned short*)alloc(2 * 512 * 128 * 2);
    unsigned short* W2T = (unsigned short*)alloc(2 * 128 * 512 * 2);
    unsigned short* WcT = (unsigned short*)alloc(16 * 128 * 2);

    hipMemsetAsync(cnt, 0, zbytes, stream);
    k_count<<<(E + 255) / 256, 256, 0, stream>>>(edst, cnt, E);
    k_scanA<<<SCAN_G, 256, 0, stream>>>(cnt, bsum, N);
    k_scanB<<<1, SCAN_G, 0, stream>>>(bsum, boff, rowptr, N);
    k_scanC<<<SCAN_G, 256, 0, stream>>>(cnt, boff, rowptr, N);
    k_fill<<<(E + 255) / 256, 256, 0, stream>>>(esrc, edst, rowptr, cursor, srcs, E);
    k_convw<<<1160, 256, 0, stream>>>(W_gcn, ff_w1, ff_w2, cls_w, WgT, W1T, W2T, WcT);
    k_convn<<<1600, 256, 0, stream>>>(nodes, nodes_bf, N * 64);

    const float invN = 1.0f / (float)N;
    const int MB = M_pad / 128;
    const unsigned short* cur_bf = nodes_bf;
    for (int L = 0; L < 2; ++L) {
        k_agg<<<(N + 3) / 4, 256, 0, stream>>>(cur_bf, rowptr, srcs, agg_bf, N);
        float* s1 = sums4 + (L * 2 + 0) * 256;
        k_mgemm<false, true, true, false, true><<<dim3(MB, 1), 256, 0, stream>>>(
            agg_bf, WgT + (size_t)L * 16384, b_gcn + L * 128, cur_bf, t, nullptr, s1,
            N, 128, 128);
        k_bnapply<<<1600, 256, 0, stream>>>(t, s1, bn1_g + L * 128, bn1_b + L * 128,
                                            x_bf, N, invN);
        k_mgemm<true, true, false, true, false><<<dim3(MB, 4), 256, 0, stream>>>(
            x_bf, W1T + (size_t)L * 65536, ff_b1 + L * 512, nullptr, nullptr, y_bf, nullptr,
            N, 512, 128);
        float* s2 = sums4 + (L * 2 + 1) * 256;
        k_mgemm<false, false, true, false, true><<<dim3(MB, 1), 256, 0, stream>>>(
            y_bf, W2T + (size_t)L * 65536, nullptr, x_bf, t, nullptr, s2,
            N, 128, 512);
        k_bnapply<<<1600, 256, 0, stream>>>(t, s2, bn2_g + L * 128, bn2_b + L * 128,
                                            x_bf, N, invN);
        cur_bf = x_bf;
    }
    k_cls<<<(M_pad / 16 + 3) / 4, 256, 0, stream>>>(x_bf, WcT, cls_b, (float*)d_out, N);
}

// Round 7
// 457.946 us; speedup vs baseline: 2.2413x; 1.1882x over previous
//
#include <hip/hip_runtime.h>
#include <stdint.h>

#define BN_EPS 1e-5f
#define SCAN_G 128

typedef short short8 __attribute__((ext_vector_type(8)));
typedef float f32x4 __attribute__((ext_vector_type(4)));

__device__ __forceinline__ unsigned short f2bf(float f) {
    union { float f; unsigned int u; } v; v.f = f;
    unsigned int r = v.u + 0x7FFFu + ((v.u >> 16) & 1u);
    return (unsigned short)(r >> 16);
}
__device__ __forceinline__ float bf2f(unsigned short h) {
    union { unsigned int u; float f; } v; v.u = (unsigned int)h << 16; return v.f;
}

// ---------------- CSR build ----------------
__global__ void k_count(const int* __restrict__ dst, int* __restrict__ cnt, int E) {
    int i = blockIdx.x * 256 + threadIdx.x;
    if (i < E) atomicAdd(cnt + dst[i], 1);
}

__global__ __launch_bounds__(256) void k_scanA(const int* __restrict__ cnt,
                                               int* __restrict__ bsum, int N) {
    __shared__ int red[256];
    int b = blockIdx.x, t = threadIdx.x;
    int C = (N + SCAN_G - 1) / SCAN_G;
    int c = (C + 255) >> 8;
    int lo = b * C + t * c;
    int hi = min(lo + c, min((b + 1) * C, N));
    int s = 0;
    for (int i = lo; i < hi; ++i) s += cnt[i];
    red[t] = s;
    __syncthreads();
    for (int off = 128; off > 0; off >>= 1) {
        if (t < off) red[t] += red[t + off];
        __syncthreads();
    }
    if (t == 0) bsum[b] = red[0];
}
__global__ void k_scanB(const int* __restrict__ bsum, int* __restrict__ boff,
                        int* __restrict__ rowptr, int N) {
    __shared__ int sh[SCAN_G];
    int t = threadIdx.x;
    int v = bsum[t];
    sh[t] = v;
    __syncthreads();
    for (int off = 1; off < SCAN_G; off <<= 1) {
        int add = (t >= off) ? sh[t - off] : 0;
        __syncthreads();
        sh[t] += add;
        __syncthreads();
    }
    boff[t] = sh[t] - v;
    if (t == SCAN_G - 1) rowptr[N] = sh[t];
}
__global__ __launch_bounds__(256) void k_scanC(const int* __restrict__ cnt,
                                               const int* __restrict__ boff,
                                               int* __restrict__ rowptr, int N) {
    __shared__ int sh[256];
    int b = blockIdx.x, t = threadIdx.x;
    int C = (N + SCAN_G - 1) / SCAN_G;
    int c = (C + 255) >> 8;
    int lo = b * C + t * c;
    int hi = min(lo + c, min((b + 1) * C, N));
    int s = 0;
    for (int i = lo; i < hi; ++i) s += cnt[i];
    sh[t] = s;
    __syncthreads();
    for (int off = 1; off < 256; off <<= 1) {
        int add = (t >= off) ? sh[t - off] : 0;
        __syncthreads();
        sh[t] += add;
        __syncthreads();
    }
    int run = boff[b] + sh[t] - s;
    for (int i = lo; i < hi; ++i) { rowptr[i] = run; run += cnt[i]; }
}

__global__ void k_fill(const int* __restrict__ src, const int* __restrict__ dst,
                       const int* __restrict__ rowptr, int* __restrict__ cursor,
                       int* __restrict__ srcs, int E) {
    int i = blockIdx.x * 256 + threadIdx.x;
    if (i < E) {
        int r = dst[i];
        int p = atomicAdd(cursor + r, 1);
        srcs[rowptr[r] + p] = src[i];
    }
}

// ---------------- weight convert+transpose to bf16 [Nn][K] (+ cls_w) ----------------
__global__ void k_convw(const float* __restrict__ Wg, const float* __restrict__ W1,
                        const float* __restrict__ W2, const float* __restrict__ Wc,
                        unsigned short* __restrict__ WgT, unsigned short* __restrict__ W1T,
                        unsigned short* __restrict__ W2T, unsigned short* __restrict__ WcT) {
    int id = blockIdx.x * 256 + threadIdx.x;
    if (id < 2 * 16384) {
        int L = id >> 14, e = id & 16383;
        int k = e >> 7, n = e & 127;
        WgT[(L << 14) + n * 128 + k] = f2bf(Wg[id]);
    } else if (id < 2 * 16384 + 2 * 65536) {
        int t = id - 2 * 16384;
        int L = t >> 16, e = t & 65535;
        int k = e >> 9, n = e & 511;
        W1T[(L << 16) + n * 128 + k] = f2bf(W1[t]);
    } else if (id < 2 * 16384 + 4 * 65536) {
        int t = id - 2 * 16384 - 2 * 65536;
        int L = t >> 16, e = t & 65535;
        int k = e >> 7, n = e & 127;
        W2T[(L << 16) + n * 512 + k] = f2bf(W2[t]);
    } else if (id < 2 * 16384 + 4 * 65536 + 2048) {
        int t = id - 2 * 16384 - 4 * 65536;
        int k = t >> 4, c = t & 15;
        WcT[c * 128 + k] = f2bf(Wc[t]);
    }
}

// nodes f32 -> bf16 (packed)
__global__ void k_convn(const float* __restrict__ nf, unsigned short* __restrict__ nbf, int n2) {
    for (int i = blockIdx.x * 256 + threadIdx.x; i < n2; i += gridDim.x * 256) {
        float2 v = ((const float2*)nf)[i];
        ((unsigned int*)nbf)[i] = ((unsigned int)f2bf(v.y) << 16) | (unsigned int)f2bf(v.x);
    }
}

// ---------------- aggregation: one wave per dst node, bf16 in/out, 4x unroll ----------------
__global__ __launch_bounds__(256) void k_agg(
    const unsigned short* __restrict__ xbf, const int* __restrict__ rowptr,
    const int* __restrict__ srcs, unsigned short* __restrict__ aggbf, int N) {
    int gw = (blockIdx.x * 256 + threadIdx.x) >> 6;
    int lane = threadIdx.x & 63;
    if (gw >= N) return;
    int lo = rowptr[gw], hi = rowptr[gw + 1];
    float ax = 0.f, ay = 0.f;
    const unsigned int* x1 = (const unsigned int*)xbf;
    int j = lo;
    for (; j + 4 <= hi; j += 4) {
        int s0 = srcs[j], s1 = srcs[j + 1], s2 = srcs[j + 2], s3 = srcs[j + 3];
        unsigned int p0 = x1[(size_t)s0 * 64 + lane];
        unsigned int p1 = x1[(size_t)s1 * 64 + lane];
        unsigned int p2 = x1[(size_t)s2 * 64 + lane];
        unsigned int p3 = x1[(size_t)s3 * 64 + lane];
        ax += bf2f((unsigned short)p0) + bf2f((unsigned short)p1)
            + bf2f((unsigned short)p2) + bf2f((unsigned short)p3);
        ay += bf2f((unsigned short)(p0 >> 16)) + bf2f((unsigned short)(p1 >> 16))
            + bf2f((unsigned short)(p2 >> 16)) + bf2f((unsigned short)(p3 >> 16));
    }
    for (; j < hi; ++j) {
        unsigned int pk = x1[(size_t)srcs[j] * 64 + lane];
        ax += bf2f((unsigned short)pk);
        ay += bf2f((unsigned short)(pk >> 16));
    }
    float w = 1.0f / fmaxf((float)(hi - lo), 1.0f);
    ((unsigned int*)aggbf)[(size_t)gw * 64 + lane] =
        ((unsigned int)f2bf(ay * w) << 16) | (unsigned int)f2bf(ax * w);
}

// ---------------- bf16 MFMA GEMM (GCN mixer): C = A @ BT^T + bias + res, +BN stats ----
template<bool RELU, bool HASB, bool RES, bool OUTBF, bool STATS>
__global__ __launch_bounds__(256) void k_mgemm(
    const unsigned short* __restrict__ A, const unsigned short* __restrict__ BT,
    const float* __restrict__ bias, const unsigned short* __restrict__ res,
    float* __restrict__ Cf, unsigned short* __restrict__ Cbf,
    float* __restrict__ sums, int M, int Nn, int K) {
    __shared__ short As[128 * 32];
    __shared__ short Bs[128 * 32];
    int tid = threadIdx.x;
    int lane = tid & 63;
    int wid = tid >> 6;
    int wr = wid >> 1, wc = wid & 1;
    int row0 = blockIdx.x * 128, col0 = blockIdx.y * 128;
    int lm = lane & 15, hk = lane >> 4;

    int sr = tid >> 2, ss = tid & 3;
    int wsw = sr * 32 + ((ss ^ ((sr >> 1) & 3)) << 3);
    const unsigned short* gA = A + (size_t)(row0 + sr) * K + ss * 8;
    const unsigned short* gB = BT + (size_t)(col0 + sr) * K + ss * 8;

    int oA[4], oB[4];
#pragma unroll
    for (int i = 0; i < 4; ++i) {
        int ra = wr * 64 + i * 16 + lm;
        oA[i] = ra * 32 + ((hk ^ ((ra >> 1) & 3)) << 3);
        int rb = wc * 64 + i * 16 + lm;
        oB[i] = rb * 32 + ((hk ^ ((rb >> 1) & 3)) << 3);
    }

    f32x4 acc[4][4] = {};
    for (int k0 = 0; k0 < K; k0 += 32) {
        short8 va0 = *(const short8*)(gA + k0);
        short8 va1 = *(const short8*)(gA + (size_t)64 * K + k0);
        short8 vb0 = *(const short8*)(gB + k0);
        short8 vb1 = *(const short8*)(gB + (size_t)64 * K + k0);
        __syncthreads();
        *(short8*)&As[wsw] = va0;
        *(short8*)&As[wsw + 64 * 32] = va1;
        *(short8*)&Bs[wsw] = vb0;
        *(short8*)&Bs[wsw + 64 * 32] = vb1;
        __syncthreads();
        short8 a[4], b[4];
#pragma unroll
        for (int i = 0; i < 4; ++i) a[i] = *(const short8*)&As[oA[i]];
#pragma unroll
        for (int j = 0; j < 4; ++j) b[j] = *(const short8*)&Bs[oB[j]];
#pragma unroll
        for (int i = 0; i < 4; ++i)
#pragma unroll
            for (int j = 0; j < 4; ++j)
                acc[i][j] = __builtin_amdgcn_mfma_f32_16x16x32_bf16(a[i], b[j], acc[i][j], 0, 0, 0);
    }

    float th_s[4] = {0.f, 0.f, 0.f, 0.f}, th_q[4] = {0.f, 0.f, 0.f, 0.f};
#pragma unroll
    for (int j = 0; j < 4; ++j) {
        int col = col0 + wc * 64 + j * 16 + lm;
        float bj = 0.f;
        if (HASB) bj = bias[col];
#pragma unroll
        for (int i = 0; i < 4; ++i) {
#pragma unroll
            for (int r = 0; r < 4; ++r) {
                int row = row0 + wr * 64 + i * 16 + hk * 4 + r;
                if (row < M) {
                    float v = acc[i][j][r] + bj;
                    if (RES) v += bf2f(res[(size_t)row * Nn + col]);
                    if (RELU) v = fmaxf(v, 0.f);
                    if (STATS) { th_s[j] += v; th_q[j] += v * v; }
                    if (OUTBF) Cbf[(size_t)row * Nn + col] = f2bf(v);
                    else Cf[(size_t)row * Nn + col] = v;
                }
            }
        }
    }
    if (STATS) {
#pragma unroll
        for (int j = 0; j < 4; ++j) {
            float s = th_s[j], q = th_q[j];
            s += __shfl_xor(s, 16); s += __shfl_xor(s, 32);
            q += __shfl_xor(q, 16); q += __shfl_xor(q, 32);
            if (hk == 0) {
                int col = col0 + wc * 64 + j * 16 + lm;
                atomicAdd(&sums[col], s);
                atomicAdd(&sums[128 + col], q);
            }
        }
    }
}

// ---------------- fused FF block: bn1-apply + FF1 + FF2 + res + BN2 stats -------------
// t (in/out) [M_pad][128] f32. y never leaves LDS. 128 rows/block, 4 waves (2x2).
// LDS row strides are odd multiples of 8 elems (136 / 40) => bank-balanced b128 reads.
__global__ __launch_bounds__(256) void k_ffused(
    float* __restrict__ t, const float* __restrict__ sums,
    const float* __restrict__ g, const float* __restrict__ b,
    const unsigned short* __restrict__ W1T, const float* __restrict__ b1,
    const unsigned short* __restrict__ W2T,
    float* __restrict__ sums2, int M, float invN) {
    __shared__ short Xs[128 * 136];   // x = bn1(t), bf16, [row][k] stride 136
    __shared__ short W1s[32 * 136];   // W1 chunk [h_local][k=128] stride 136
    __shared__ short Ys[128 * 40];    // y chunk  [row][h_local=32] stride 40
    __shared__ short W2s[128 * 40];   // W2 chunk [n][h_local=32] stride 40
    __shared__ float sa[128], sc[128];

    int tid = threadIdx.x;
    int row0 = blockIdx.x * 128;
    if (tid < 128) {
        float m = sums[tid] * invN;
        float var = sums[128 + tid] * invN - m * m;
        float a = g[tid] * rsqrtf(var + BN_EPS);
        sa[tid] = a; sc[tid] = b[tid] - m * a;
    }
    __syncthreads();

    // prologue: load t slice, bn1, pack bf16 into Xs
    {
        int pc = (tid & 31) * 4;    // col base (0..124)
        int pr = tid >> 5;          // row base 0..7
        float a0 = sa[pc], a1 = sa[pc + 1], a2 = sa[pc + 2], a3 = sa[pc + 3];
        float c0 = sc[pc], c1 = sc[pc + 1], c2 = sc[pc + 2], c3 = sc[pc + 3];
#pragma unroll
        for (int i = 0; i < 16; ++i) {
            int row = pr + i * 8;
            float4 v = *(const float4*)(t + (size_t)(row0 + row) * 128 + pc);
            unsigned int lo = ((unsigned)f2bf(v.y * a1 + c1) << 16) | (unsigned)f2bf(v.x * a0 + c0);
            unsigned int hi = ((unsigned)f2bf(v.w * a3 + c3) << 16) | (unsigned)f2bf(v.z * a2 + c2);
            *(uint2*)((char*)Xs + row * 272 + pc * 2) = make_uint2(lo, hi);
        }
    }

    int lane = tid & 63, wid = tid >> 6;
    int wr = wid >> 1, wc = wid & 1;
    int lm = lane & 15, hk = lane >> 4;

    f32x4 tacc[4][4] = {};
    for (int hc = 0; hc < 16; ++hc) {
        // stage next W1/W2 chunk: issue loads, barrier (protect prior reads), write
        int rw1 = tid >> 3, sl1 = (tid & 7) * 2;
        const unsigned short* s1p = W1T + (size_t)(hc * 32 + rw1) * 128 + sl1 * 8;
        short8 wa = *(const short8*)s1p;
        short8 wb = *(const short8*)(s1p + 8);
        int rw2 = tid >> 1, sl2 = (tid & 1) * 2;
        const unsigned short* s2p = W2T + (size_t)rw2 * 512 + hc * 32 + sl2 * 8;
        short8 wcv = *(const short8*)s2p;
        short8 wdv = *(const short8*)(s2p + 8);
        __syncthreads();
        *(short8*)&W1s[rw1 * 136 + sl1 * 8] = wa;
        *(short8*)&W1s[rw1 * 136 + (sl1 + 1) * 8] = wb;
        *(short8*)&W2s[rw2 * 40 + sl2 * 8] = wcv;
        *(short8*)&W2s[rw2 * 40 + (sl2 + 1) * 8] = wdv;
        __syncthreads();

        // y = relu(Xs @ W1c + b1c): wave tile 64x16, K=128
        f32x4 yacc[4] = {};
#pragma unroll
        for (int k0 = 0; k0 < 4; ++k0) {
            int s = k0 * 4 + hk;
            short8 bfrag = *(const short8*)&W1s[(wc * 16 + lm) * 136 + s * 8];
#pragma unroll
            for (int i = 0; i < 4; ++i) {
                short8 afrag = *(const short8*)&Xs[(wr * 64 + i * 16 + lm) * 136 + s * 8];
                yacc[i] = __builtin_amdgcn_mfma_f32_16x16x32_bf16(afrag, bfrag, yacc[i], 0, 0, 0);
            }
        }
        float bb = b1[hc * 32 + wc * 16 + lm];
#pragma unroll
        for (int i = 0; i < 4; ++i)
#pragma unroll
            for (int r = 0; r < 4; ++r) {
                float v = fmaxf(yacc[i][r] + bb, 0.f);
                Ys[(wr * 64 + i * 16 + hk * 4 + r) * 40 + wc * 16 + lm] = (short)f2bf(v);
            }
        __syncthreads();

        // tacc += Ys @ W2c: wave tile 64x64, K=32
#pragma unroll
        for (int j = 0; j < 4; ++j) {
            short8 bfrag = *(const short8*)&W2s[(wc * 64 + j * 16 + lm) * 40 + hk * 8];
#pragma unroll
            for (int i = 0; i < 4; ++i) {
                short8 afrag = *(const short8*)&Ys[(wr * 64 + i * 16 + lm) * 40 + hk * 8];
                tacc[i][j] = __builtin_amdgcn_mfma_f32_16x16x32_bf16(afrag, bfrag, tacc[i][j], 0, 0, 0);
            }
        }
    }

    // epilogue: t = tacc + res(Xs), BN2 stats, write f32
    float th_s[4] = {0.f, 0.f, 0.f, 0.f}, th_q[4] = {0.f, 0.f, 0.f, 0.f};
#pragma unroll
    for (int j = 0; j < 4; ++j) {
        int col = wc * 64 + j * 16 + lm;
#pragma unroll
        for (int i = 0; i < 4; ++i) {
#pragma unroll
            for (int r = 0; r < 4; ++r) {
                int row = wr * 64 + i * 16 + hk * 4 + r;
                int grow = row0 + row;
                if (grow < M) {
                    float v = tacc[i][j][r] + bf2f((unsigned short)Xs[row * 136 + col]);
                    th_s[j] += v; th_q[j] += v * v;
                    t[(size_t)grow * 128 + col] = v;
                }
            }
        }
    }
#pragma unroll
    for (int j = 0; j < 4; ++j) {
        float s = th_s[j], q = th_q[j];
        s += __shfl_xor(s, 16); s += __shfl_xor(s, 32);
        q += __shfl_xor(q, 16); q += __shfl_xor(q, 32);
        if (hk == 0) {
            int col = wc * 64 + j * 16 + lm;
            atomicAdd(&sums2[col], s);
            atomicAdd(&sums2[128 + col], q);
        }
    }
}

// ---------------- BN apply: x_bf = bf16((t - m) * a + b) ----------------
__global__ __launch_bounds__(256) void k_bnapply(
    const float* __restrict__ t, const float* __restrict__ sums,
    const float* __restrict__ g, const float* __restrict__ b,
    unsigned short* __restrict__ xbf, int N, float invN) {
    __shared__ float sa[128], sc[128];
    int tid = threadIdx.x;
    if (tid < 128) {
        float m = sums[tid] * invN;
        float var = sums[128 + tid] * invN - m * m;
        float a = g[tid] * rsqrtf(var + BN_EPS);
        sa[tid] = a; sc[tid] = b[tid] - m * a;
    }
    __syncthreads();
    int total4 = N * 32;
    for (int i = blockIdx.x * 256 + tid; i < total4; i += gridDim.x * 256) {
        int c4 = (i & 31) * 4;
        float4 v = ((const float4*)t)[i];
        float ox = v.x * sa[c4 + 0] + sc[c4 + 0];
        float oy = v.y * sa[c4 + 1] + sc[c4 + 1];
        float oz = v.z * sa[c4 + 2] + sc[c4 + 2];
        float ow = v.w * sa[c4 + 3] + sc[c4 + 3];
        uint2 pk;
        pk.x = ((unsigned)f2bf(oy) << 16) | (unsigned)f2bf(ox);
        pk.y = ((unsigned)f2bf(ow) << 16) | (unsigned)f2bf(oz);
        ((uint2*)xbf)[i] = pk;
    }
}

// ---------------- classifier: MFMA, one wave per 16-row tile ----------------
__global__ __launch_bounds__(256) void k_cls(
    const unsigned short* __restrict__ xbf, const unsigned short* __restrict__ wT,
    const float* __restrict__ bias, float* __restrict__ out, int N) {
    int wv = (blockIdx.x * 256 + threadIdx.x) >> 6;
    int lane = threadIdx.x & 63;
    int lm = lane & 15, hk = lane >> 4;
    int r0 = wv * 16;
    f32x4 acc = {};
    const unsigned short* xr = xbf + (size_t)(r0 + lm) * 128 + hk * 8;
    const unsigned short* wr = wT + lm * 128 + hk * 8;
#pragma unroll
    for (int ks = 0; ks < 4; ++ks) {
        short8 a = *(const short8*)(xr + ks * 32);
        short8 b = *(const short8*)(wr + ks * 32);
        acc = __builtin_amdgcn_mfma_f32_16x16x32_bf16(a, b, acc, 0, 0, 0);
    }
    float bv = bias[lm];
#pragma unroll
    for (int r = 0; r < 4; ++r) {
        int row = r0 + hk * 4 + r;
        if (row < N) out[(size_t)row * 16 + lm] = acc[r] + bv;
    }
}

extern "C" void kernel_launch(void* const* d_in, const int* in_sizes, int n_in,
                              void* d_out, int out_size, void* d_ws, size_t ws_size,
                              hipStream_t stream) {
    const float* nodes = (const float*)d_in[0];
    const float* W_gcn = (const float*)d_in[1];
    const float* b_gcn = (const float*)d_in[2];
    const float* bn1_g = (const float*)d_in[3];
    const float* bn1_b = (const float*)d_in[4];
    const float* bn2_g = (const float*)d_in[5];
    const float* bn2_b = (const float*)d_in[6];
    const float* ff_w1 = (const float*)d_in[7];
    const float* ff_b1 = (const float*)d_in[8];
    const float* ff_w2 = (const float*)d_in[9];
    const float* cls_w = (const float*)d_in[10];
    const float* cls_b = (const float*)d_in[11];
    const int* esrc = (const int*)d_in[12];
    const int* edst = (const int*)d_in[13];
    const int N = in_sizes[0] / 128;
    const int E = in_sizes[12];
    const int M_pad = (N + 127) & ~127;

    char* p = (char*)d_ws;
    auto alloc = [&](size_t bytes) {
        void* r = (void*)p;
        p += (bytes + 255) & ~(size_t)255;
        return r;
    };
    // zero-region: cnt | cursor | 4x sums  (one memset)
    int* cnt      = (int*)alloc((size_t)N * 4);
    int* cursor   = (int*)alloc((size_t)N * 4);
    float* sums4  = (float*)alloc(4 * 256 * 4);
    size_t zbytes = (size_t)((char*)sums4 + 4 * 256 * 4 - (char*)cnt);

    float* t    = (float*)alloc((size_t)M_pad * 128 * 4);
    int* rowptr = (int*)alloc((size_t)(N + 1) * 4);
    int* srcs   = (int*)alloc((size_t)E * 4);
    int* bsum   = (int*)alloc(SCAN_G * 4);
    int* boff   = (int*)alloc(SCAN_G * 4);
    unsigned short* nodes_bf = (unsigned short*)alloc((size_t)M_pad * 128 * 2);
    unsigned short* agg_bf   = (unsigned short*)alloc((size_t)M_pad * 128 * 2);
    unsigned short* x_bf     = (unsigned short*)alloc((size_t)M_pad * 128 * 2);
    unsigned short* WgT = (unsigned short*)alloc(2 * 128 * 128 * 2);
    unsigned short* W1T = (unsigned short*)alloc(2 * 512 * 128 * 2);
    unsigned short* W2T = (unsigned short*)alloc(2 * 128 * 512 * 2);
    unsigned short* WcT = (unsigned short*)alloc(16 * 128 * 2);

    hipMemsetAsync(cnt, 0, zbytes, stream);
    k_count<<<(E + 255) / 256, 256, 0, stream>>>(edst, cnt, E);
    k_scanA<<<SCAN_G, 256, 0, stream>>>(cnt, bsum, N);
    k_scanB<<<1, SCAN_G, 0, stream>>>(bsum, boff, rowptr, N);
    k_scanC<<<SCAN_G, 256, 0, stream>>>(cnt, boff, rowptr, N);
    k_fill<<<(E + 255) / 256, 256, 0, stream>>>(esrc, edst, rowptr, cursor, srcs, E);
    k_convw<<<1160, 256, 0, stream>>>(W_gcn, ff_w1, ff_w2, cls_w, WgT, W1T, W2T, WcT);
    k_convn<<<1600, 256, 0, stream>>>(nodes, nodes_bf, N * 64);

    const float invN = 1.0f / (float)N;
    const int MB = M_pad / 128;
    const unsigned short* cur_bf = nodes_bf;
    for (int L = 0; L < 2; ++L) {
        k_agg<<<(N + 3) / 4, 256, 0, stream>>>(cur_bf, rowptr, srcs, agg_bf, N);
        float* s1 = sums4 + (L * 2 + 0) * 256;
        float* s2 = sums4 + (L * 2 + 1) * 256;
        // GCN: t = agg@Wg + b + res(cur_bf), f32 out, fused BN1 stats
        k_mgemm<false, true, true, false, true><<<dim3(MB, 1), 256, 0, stream>>>(
            agg_bf, WgT + (size_t)L * 16384, b_gcn + L * 128, cur_bf, t, nullptr, s1,
            N, 128, 128);
        // fused: bn1-apply + FF1 + FF2 + residual + BN2 stats (y stays in LDS)
        k_ffused<<<MB, 256, 0, stream>>>(
            t, s1, bn1_g + L * 128, bn1_b + L * 128,
            W1T + (size_t)L * 65536, ff_b1 + L * 512, W2T + (size_t)L * 65536,
            s2, N, invN);
        k_bnapply<<<1600, 256, 0, stream>>>(t, s2, bn2_g + L * 128, bn2_b + L * 128,
                                            x_bf, N, invN);
        cur_bf = x_bf;
    }
    k_cls<<<(M_pad / 16 + 3) / 4, 256, 0, stream>>>(x_bf, WcT, cls_b, (float*)d_out, N);
}

// Round 8
// 454.645 us; speedup vs baseline: 2.2576x; 1.0073x over previous
//
#include <hip/hip_runtime.h>
#include <stdint.h>

#define BN_EPS 1e-5f
#define SCAN_G 128

typedef short short8 __attribute__((ext_vector_type(8)));
typedef float f32x4 __attribute__((ext_vector_type(4)));

__device__ __forceinline__ unsigned short f2bf(float f) {
    union { float f; unsigned int u; } v; v.f = f;
    unsigned int r = v.u + 0x7FFFu + ((v.u >> 16) & 1u);
    return (unsigned short)(r >> 16);
}
__device__ __forceinline__ float bf2f(unsigned short h) {
    union { unsigned int u; float f; } v; v.u = (unsigned int)h << 16; return v.f;
}

// ---------------- CSR build ----------------
__global__ void k_count(const int* __restrict__ dst, int* __restrict__ cnt, int E) {
    int i = blockIdx.x * 256 + threadIdx.x;
    if (i < E) atomicAdd(cnt + dst[i], 1);
}

__global__ __launch_bounds__(256) void k_scanA(const int* __restrict__ cnt,
                                               int* __restrict__ bsum, int N) {
    __shared__ int red[256];
    int b = blockIdx.x, t = threadIdx.x;
    int C = (N + SCAN_G - 1) / SCAN_G;
    int c = (C + 255) >> 8;
    int lo = b * C + t * c;
    int hi = min(lo + c, min((b + 1) * C, N));
    int s = 0;
    for (int i = lo; i < hi; ++i) s += cnt[i];
    red[t] = s;
    __syncthreads();
    for (int off = 128; off > 0; off >>= 1) {
        if (t < off) red[t] += red[t + off];
        __syncthreads();
    }
    if (t == 0) bsum[b] = red[0];
}
__global__ void k_scanB(const int* __restrict__ bsum, int* __restrict__ boff,
                        int* __restrict__ rowptr, int N) {
    __shared__ int sh[SCAN_G];
    int t = threadIdx.x;
    int v = bsum[t];
    sh[t] = v;
    __syncthreads();
    for (int off = 1; off < SCAN_G; off <<= 1) {
        int add = (t >= off) ? sh[t - off] : 0;
        __syncthreads();
        sh[t] += add;
        __syncthreads();
    }
    boff[t] = sh[t] - v;
    if (t == SCAN_G - 1) rowptr[N] = sh[t];
}
__global__ __launch_bounds__(256) void k_scanC(const int* __restrict__ cnt,
                                               const int* __restrict__ boff,
                                               int* __restrict__ rowptr, int N) {
    __shared__ int sh[256];
    int b = blockIdx.x, t = threadIdx.x;
    int C = (N + SCAN_G - 1) / SCAN_G;
    int c = (C + 255) >> 8;
    int lo = b * C + t * c;
    int hi = min(lo + c, min((b + 1) * C, N));
    int s = 0;
    for (int i = lo; i < hi; ++i) s += cnt[i];
    sh[t] = s;
    __syncthreads();
    for (int off = 1; off < 256; off <<= 1) {
        int add = (t >= off) ? sh[t - off] : 0;
        __syncthreads();
        sh[t] += add;
        __syncthreads();
    }
    int run = boff[b] + sh[t] - s;
    for (int i = lo; i < hi; ++i) { rowptr[i] = run; run += cnt[i]; }
}

__global__ void k_fill(const int* __restrict__ src, const int* __restrict__ dst,
                       const int* __restrict__ rowptr, int* __restrict__ cursor,
                       int* __restrict__ srcs, int E) {
    int i = blockIdx.x * 256 + threadIdx.x;
    if (i < E) {
        int r = dst[i];
        int p = atomicAdd(cursor + r, 1);
        srcs[rowptr[r] + p] = src[i];
    }
}

// ---------------- weight convert+transpose to bf16 [Nn][K] (+ cls_w) ----------------
__global__ void k_convw(const float* __restrict__ Wg, const float* __restrict__ W1,
                        const float* __restrict__ W2, const float* __restrict__ Wc,
                        unsigned short* __restrict__ WgT, unsigned short* __restrict__ W1T,
                        unsigned short* __restrict__ W2T, unsigned short* __restrict__ WcT) {
    int id = blockIdx.x * 256 + threadIdx.x;
    if (id < 2 * 16384) {
        int L = id >> 14, e = id & 16383;
        int k = e >> 7, n = e & 127;
        WgT[(L << 14) + n * 128 + k] = f2bf(Wg[id]);
    } else if (id < 2 * 16384 + 2 * 65536) {
        int t = id - 2 * 16384;
        int L = t >> 16, e = t & 65535;
        int k = e >> 9, n = e & 511;
        W1T[(L << 16) + n * 128 + k] = f2bf(W1[t]);
    } else if (id < 2 * 16384 + 4 * 65536) {
        int t = id - 2 * 16384 - 2 * 65536;
        int L = t >> 16, e = t & 65535;
        int k = e >> 7, n = e & 127;
        W2T[(L << 16) + n * 512 + k] = f2bf(W2[t]);
    } else if (id < 2 * 16384 + 4 * 65536 + 2048) {
        int t = id - 2 * 16384 - 4 * 65536;
        int k = t >> 4, c = t & 15;
        WcT[c * 128 + k] = f2bf(Wc[t]);
    }
}

// nodes f32 -> bf16 (packed)
__global__ void k_convn(const float* __restrict__ nf, unsigned short* __restrict__ nbf, int n2) {
    for (int i = blockIdx.x * 256 + threadIdx.x; i < n2; i += gridDim.x * 256) {
        float2 v = ((const float2*)nf)[i];
        ((unsigned int*)nbf)[i] = ((unsigned int)f2bf(v.y) << 16) | (unsigned int)f2bf(v.x);
    }
}

// ---------------- aggregation: one HALF-WAVE (32 lanes) per dst node ----------------
__global__ __launch_bounds__(256) void k_agg(
    const unsigned short* __restrict__ xbf, const int* __restrict__ rowptr,
    const int* __restrict__ srcs, unsigned short* __restrict__ aggbf, int N) {
    int gh = (blockIdx.x * 256 + threadIdx.x) >> 5;
    int l = threadIdx.x & 31;
    if (gh >= N) return;
    int lo = rowptr[gh], hi = rowptr[gh + 1];
    float a0 = 0.f, a1 = 0.f, a2 = 0.f, a3 = 0.f;
    const uint2* x2 = (const uint2*)xbf;
    int j = lo;
    for (; j + 4 <= hi; j += 4) {
        int s0 = srcs[j], s1 = srcs[j + 1], s2 = srcs[j + 2], s3 = srcs[j + 3];
        uint2 p0 = x2[(size_t)s0 * 32 + l];
        uint2 p1 = x2[(size_t)s1 * 32 + l];
        uint2 p2 = x2[(size_t)s2 * 32 + l];
        uint2 p3 = x2[(size_t)s3 * 32 + l];
        a0 += bf2f((unsigned short)p0.x) + bf2f((unsigned short)p1.x)
            + bf2f((unsigned short)p2.x) + bf2f((unsigned short)p3.x);
        a1 += bf2f((unsigned short)(p0.x >> 16)) + bf2f((unsigned short)(p1.x >> 16))
            + bf2f((unsigned short)(p2.x >> 16)) + bf2f((unsigned short)(p3.x >> 16));
        a2 += bf2f((unsigned short)p0.y) + bf2f((unsigned short)p1.y)
            + bf2f((unsigned short)p2.y) + bf2f((unsigned short)p3.y);
        a3 += bf2f((unsigned short)(p0.y >> 16)) + bf2f((unsigned short)(p1.y >> 16))
            + bf2f((unsigned short)(p2.y >> 16)) + bf2f((unsigned short)(p3.y >> 16));
    }
    for (; j < hi; ++j) {
        uint2 p = x2[(size_t)srcs[j] * 32 + l];
        a0 += bf2f((unsigned short)p.x); a1 += bf2f((unsigned short)(p.x >> 16));
        a2 += bf2f((unsigned short)p.y); a3 += bf2f((unsigned short)(p.y >> 16));
    }
    float iw = 1.0f / fmaxf((float)(hi - lo), 1.0f);
    uint2 o;
    o.x = ((unsigned)f2bf(a1 * iw) << 16) | (unsigned)f2bf(a0 * iw);
    o.y = ((unsigned)f2bf(a3 * iw) << 16) | (unsigned)f2bf(a2 * iw);
    ((uint2*)aggbf)[(size_t)gh * 32 + l] = o;
}

// ---------------- bf16 MFMA GEMM (GCN mixer): C = A @ BT^T + bias + res, +BN stats ----
template<bool RELU, bool HASB, bool RES, bool OUTBF, bool STATS>
__global__ __launch_bounds__(256) void k_mgemm(
    const unsigned short* __restrict__ A, const unsigned short* __restrict__ BT,
    const float* __restrict__ bias, const unsigned short* __restrict__ res,
    float* __restrict__ Cf, unsigned short* __restrict__ Cbf,
    float* __restrict__ sums, int M, int Nn, int K) {
    __shared__ short As[128 * 32];
    __shared__ short Bs[128 * 32];
    int tid = threadIdx.x;
    int lane = tid & 63;
    int wid = tid >> 6;
    int wr = wid >> 1, wc = wid & 1;
    int row0 = blockIdx.x * 128, col0 = blockIdx.y * 128;
    int lm = lane & 15, hk = lane >> 4;

    int sr = tid >> 2, ss = tid & 3;
    int wsw = sr * 32 + ((ss ^ ((sr >> 1) & 3)) << 3);
    const unsigned short* gA = A + (size_t)(row0 + sr) * K + ss * 8;
    const unsigned short* gB = BT + (size_t)(col0 + sr) * K + ss * 8;

    int oA[4], oB[4];
#pragma unroll
    for (int i = 0; i < 4; ++i) {
        int ra = wr * 64 + i * 16 + lm;
        oA[i] = ra * 32 + ((hk ^ ((ra >> 1) & 3)) << 3);
        int rb = wc * 64 + i * 16 + lm;
        oB[i] = rb * 32 + ((hk ^ ((rb >> 1) & 3)) << 3);
    }

    f32x4 acc[4][4] = {};
    for (int k0 = 0; k0 < K; k0 += 32) {
        short8 va0 = *(const short8*)(gA + k0);
        short8 va1 = *(const short8*)(gA + (size_t)64 * K + k0);
        short8 vb0 = *(const short8*)(gB + k0);
        short8 vb1 = *(const short8*)(gB + (size_t)64 * K + k0);
        __syncthreads();
        *(short8*)&As[wsw] = va0;
        *(short8*)&As[wsw + 64 * 32] = va1;
        *(short8*)&Bs[wsw] = vb0;
        *(short8*)&Bs[wsw + 64 * 32] = vb1;
        __syncthreads();
        short8 a[4], b[4];
#pragma unroll
        for (int i = 0; i < 4; ++i) a[i] = *(const short8*)&As[oA[i]];
#pragma unroll
        for (int j = 0; j < 4; ++j) b[j] = *(const short8*)&Bs[oB[j]];
#pragma unroll
        for (int i = 0; i < 4; ++i)
#pragma unroll
            for (int j = 0; j < 4; ++j)
                acc[i][j] = __builtin_amdgcn_mfma_f32_16x16x32_bf16(a[i], b[j], acc[i][j], 0, 0, 0);
    }

    float th_s[4] = {0.f, 0.f, 0.f, 0.f}, th_q[4] = {0.f, 0.f, 0.f, 0.f};
#pragma unroll
    for (int j = 0; j < 4; ++j) {
        int col = col0 + wc * 64 + j * 16 + lm;
        float bj = 0.f;
        if (HASB) bj = bias[col];
#pragma unroll
        for (int i = 0; i < 4; ++i) {
#pragma unroll
            for (int r = 0; r < 4; ++r) {
                int row = row0 + wr * 64 + i * 16 + hk * 4 + r;
                if (row < M) {
                    float v = acc[i][j][r] + bj;
                    if (RES) v += bf2f(res[(size_t)row * Nn + col]);
                    if (RELU) v = fmaxf(v, 0.f);
                    if (STATS) { th_s[j] += v; th_q[j] += v * v; }
                    if (OUTBF) Cbf[(size_t)row * Nn + col] = f2bf(v);
                    else Cf[(size_t)row * Nn + col] = v;
                }
            }
        }
    }
    if (STATS) {
#pragma unroll
        for (int j = 0; j < 4; ++j) {
            float s = th_s[j], q = th_q[j];
            s += __shfl_xor(s, 16); s += __shfl_xor(s, 32);
            q += __shfl_xor(q, 16); q += __shfl_xor(q, 32);
            if (hk == 0) {
                int col = col0 + wc * 64 + j * 16 + lm;
                atomicAdd(&sums[col], s);
                atomicAdd(&sums[128 + col], q);
            }
        }
    }
}

// ---------------- fused FF block v2: bn1 + FF1 + FF2 + res + BN2 stats ----------------
// 64 rows/block, 4 waves x 16 rows. y^T lives in registers; cross-lane repack via
// ds_bpermute (8/chunk). No Ys LDS => no transpose bank conflicts.
__global__ __launch_bounds__(256, 4) void k_ffused(
    float* __restrict__ t, const float* __restrict__ sums,
    const float* __restrict__ g, const float* __restrict__ b,
    const unsigned short* __restrict__ W1T, const float* __restrict__ b1,
    const unsigned short* __restrict__ W2T,
    float* __restrict__ sums2, int M, float invN) {
    __shared__ short Xs[64 * 136];    // 17.4KB  bn1(t) bf16
    __shared__ short W1s[32 * 136];   // 8.7KB   W1 chunk [h][k=128]
    __shared__ short W2s[128 * 40];   // 10.2KB  W2 chunk [n][h=32]
    __shared__ float sa[128], sc[128];
    __shared__ float b1s[512];
    __shared__ float ssum[256];

    int tid = threadIdx.x;
    int row0 = blockIdx.x * 64;
    if (tid < 128) {
        float m = sums[tid] * invN;
        float var = sums[128 + tid] * invN - m * m;
        float a = g[tid] * rsqrtf(var + BN_EPS);
        sa[tid] = a; sc[tid] = b[tid] - m * a;
    }
    b1s[tid] = b1[tid];
    b1s[tid + 256] = b1[tid + 256];
    ssum[tid] = 0.f;
    __syncthreads();

    // prologue: 64 rows of t -> bn1 -> bf16 Xs
    {
        int pc = (tid & 31) * 4;
        int pr = tid >> 5;  // 0..7
        float a0 = sa[pc], a1 = sa[pc + 1], a2 = sa[pc + 2], a3 = sa[pc + 3];
        float c0 = sc[pc], c1 = sc[pc + 1], c2 = sc[pc + 2], c3 = sc[pc + 3];
#pragma unroll
        for (int i = 0; i < 8; ++i) {
            int row = pr + i * 8;
            float4 v = *(const float4*)(t + (size_t)(row0 + row) * 128 + pc);
            unsigned int lo = ((unsigned)f2bf(v.y * a1 + c1) << 16) | (unsigned)f2bf(v.x * a0 + c0);
            unsigned int hi = ((unsigned)f2bf(v.w * a3 + c3) << 16) | (unsigned)f2bf(v.z * a2 + c2);
            *(uint2*)((char*)Xs + row * 272 + pc * 2) = make_uint2(lo, hi);
        }
    }

    int lane = tid & 63, wv = tid >> 6;
    int lm = lane & 15, hk = lane >> 4;
    int mh = hk & 2;                       // m-select for bpermute repack
    int idxA = 4 * (lm + 16 * ((2 * hk) & 3));
    int idxB = idxA + 64;
    int xbase = (wv * 16 + lm) * 136;

    f32x4 tacc[8] = {};
    for (int hc = 0; hc < 16; ++hc) {
        // stage W1 chunk (32x128) and W2 chunk (128x32)
        int rw1 = tid >> 3, sl1 = (tid & 7) * 16;
        const unsigned short* s1p = W1T + (size_t)(hc * 32 + rw1) * 128 + sl1;
        short8 wla = *(const short8*)s1p;
        short8 wlb = *(const short8*)(s1p + 8);
        int rw2 = tid >> 1, sl2 = (tid & 1) * 16;
        const unsigned short* s2p = W2T + (size_t)rw2 * 512 + hc * 32 + sl2;
        short8 wlc = *(const short8*)s2p;
        short8 wld = *(const short8*)(s2p + 8);
        __syncthreads();
        *(short8*)&W1s[rw1 * 136 + sl1] = wla;
        *(short8*)&W1s[rw1 * 136 + sl1 + 8] = wlb;
        *(short8*)&W2s[rw2 * 40 + sl2] = wlc;
        *(short8*)&W2s[rw2 * 40 + sl2 + 8] = wld;
        __syncthreads();

        // FF1 transposed: yT = W1c(h x k) @ X^T(k x row); D: lm=row, regs=h
        f32x4 y0 = {}, y1 = {};
#pragma unroll
        for (int k0 = 0; k0 < 4; ++k0) {
            short8 xf  = *(const short8*)&Xs[xbase + hk * 8 + k0 * 32];
            short8 w1a = *(const short8*)&W1s[lm * 136 + hk * 8 + k0 * 32];
            short8 w1b = *(const short8*)&W1s[(16 + lm) * 136 + hk * 8 + k0 * 32];
            y0 = __builtin_amdgcn_mfma_f32_16x16x32_bf16(w1a, xf, y0, 0, 0, 0);
            y1 = __builtin_amdgcn_mfma_f32_16x16x32_bf16(w1b, xf, y1, 0, 0, 0);
        }
        // bias + relu + pack to bf16 pairs (h = hc*32 + m*16 + hk*4 + r)
        int bb = hc * 32 + hk * 4;
        float v00 = fmaxf(y0[0] + b1s[bb + 0], 0.f);
        float v01 = fmaxf(y0[1] + b1s[bb + 1], 0.f);
        float v02 = fmaxf(y0[2] + b1s[bb + 2], 0.f);
        float v03 = fmaxf(y0[3] + b1s[bb + 3], 0.f);
        float v10 = fmaxf(y1[0] + b1s[bb + 16], 0.f);
        float v11 = fmaxf(y1[1] + b1s[bb + 17], 0.f);
        float v12 = fmaxf(y1[2] + b1s[bb + 18], 0.f);
        float v13 = fmaxf(y1[3] + b1s[bb + 19], 0.f);
        int pk00 = (int)(((unsigned)f2bf(v01) << 16) | (unsigned)f2bf(v00));
        int pk01 = (int)(((unsigned)f2bf(v03) << 16) | (unsigned)f2bf(v02));
        int pk10 = (int)(((unsigned)f2bf(v11) << 16) | (unsigned)f2bf(v10));
        int pk11 = (int)(((unsigned)f2bf(v13) << 16) | (unsigned)f2bf(v12));
        // repack: lane(lm,hk) gathers h = 8hk..8hk+7 for node-row lm
        int q0a = __builtin_amdgcn_ds_bpermute(idxA, pk00);
        int q1a = __builtin_amdgcn_ds_bpermute(idxA, pk01);
        int q2a = __builtin_amdgcn_ds_bpermute(idxA, pk10);
        int q3a = __builtin_amdgcn_ds_bpermute(idxA, pk11);
        int q0b = __builtin_amdgcn_ds_bpermute(idxB, pk00);
        int q1b = __builtin_amdgcn_ds_bpermute(idxB, pk01);
        int q2b = __builtin_amdgcn_ds_bpermute(idxB, pk10);
        int q3b = __builtin_amdgcn_ds_bpermute(idxB, pk11);
        union { int u[4]; short8 s; } yf;
        yf.u[0] = mh ? q2a : q0a;
        yf.u[1] = mh ? q3a : q1a;
        yf.u[2] = mh ? q2b : q0b;
        yf.u[3] = mh ? q3b : q1b;
        // FF2: tacc += y(row x h) @ W2c(h x n); D: lm=n, regs=row
#pragma unroll
        for (int nc = 0; nc < 8; ++nc) {
            short8 w2f = *(const short8*)&W2s[(nc * 16 + lm) * 40 + hk * 8];
            tacc[nc] = __builtin_amdgcn_mfma_f32_16x16x32_bf16(yf.s, w2f, tacc[nc], 0, 0, 0);
        }
    }

    // epilogue: t = tacc + res, BN2 stats
#pragma unroll
    for (int nc = 0; nc < 8; ++nc) {
        int n = nc * 16 + lm;
        float s = 0.f, q = 0.f;
#pragma unroll
        for (int r = 0; r < 4; ++r) {
            int rloc = wv * 16 + hk * 4 + r;
            int grow = row0 + rloc;
            float v = tacc[nc][r] + bf2f((unsigned short)Xs[rloc * 136 + n]);
            if (grow < M) {
                t[(size_t)grow * 128 + n] = v;
                s += v; q += v * v;
            }
        }
        s += __shfl_xor(s, 16); s += __shfl_xor(s, 32);
        q += __shfl_xor(q, 16); q += __shfl_xor(q, 32);
        if (hk == 0) {
            atomicAdd(&ssum[n], s);
            atomicAdd(&ssum[128 + n], q);
        }
    }
    __syncthreads();
    atomicAdd(&sums2[tid], ssum[tid]);
}

// ---------------- BN apply: x_bf = bf16((t - m) * a + b) ----------------
__global__ __launch_bounds__(256) void k_bnapply(
    const float* __restrict__ t, const float* __restrict__ sums,
    const float* __restrict__ g, const float* __restrict__ b,
    unsigned short* __restrict__ xbf, int N, float invN) {
    __shared__ float sa[128], sc[128];
    int tid = threadIdx.x;
    if (tid < 128) {
        float m = sums[tid] * invN;
        float var = sums[128 + tid] * invN - m * m;
        float a = g[tid] * rsqrtf(var + BN_EPS);
        sa[tid] = a; sc[tid] = b[tid] - m * a;
    }
    __syncthreads();
    int total4 = N * 32;
    for (int i = blockIdx.x * 256 + tid; i < total4; i += gridDim.x * 256) {
        int c4 = (i & 31) * 4;
        float4 v = ((const float4*)t)[i];
        float ox = v.x * sa[c4 + 0] + sc[c4 + 0];
        float oy = v.y * sa[c4 + 1] + sc[c4 + 1];
        float oz = v.z * sa[c4 + 2] + sc[c4 + 2];
        float ow = v.w * sa[c4 + 3] + sc[c4 + 3];
        uint2 pk;
        pk.x = ((unsigned)f2bf(oy) << 16) | (unsigned)f2bf(ox);
        pk.y = ((unsigned)f2bf(ow) << 16) | (unsigned)f2bf(oz);
        ((uint2*)xbf)[i] = pk;
    }
}

// ---------------- classifier: MFMA, one wave per 16-row tile ----------------
__global__ __launch_bounds__(256) void k_cls(
    const unsigned short* __restrict__ xbf, const unsigned short* __restrict__ wT,
    const float* __restrict__ bias, float* __restrict__ out, int N) {
    int wv = (blockIdx.x * 256 + threadIdx.x) >> 6;
    int lane = threadIdx.x & 63;
    int lm = lane & 15, hk = lane >> 4;
    int r0 = wv * 16;
    f32x4 acc = {};
    const unsigned short* xr = xbf + (size_t)(r0 + lm) * 128 + hk * 8;
    const unsigned short* wr = wT + lm * 128 + hk * 8;
#pragma unroll
    for (int ks = 0; ks < 4; ++ks) {
        short8 a = *(const short8*)(xr + ks * 32);
        short8 b = *(const short8*)(wr + ks * 32);
        acc = __builtin_amdgcn_mfma_f32_16x16x32_bf16(a, b, acc, 0, 0, 0);
    }
    float bv = bias[lm];
#pragma unroll
    for (int r = 0; r < 4; ++r) {
        int row = r0 + hk * 4 + r;
        if (row < N) out[(size_t)row * 16 + lm] = acc[r] + bv;
    }
}

extern "C" void kernel_launch(void* const* d_in, const int* in_sizes, int n_in,
                              void* d_out, int out_size, void* d_ws, size_t ws_size,
                              hipStream_t stream) {
    const float* nodes = (const float*)d_in[0];
    const float* W_gcn = (const float*)d_in[1];
    const float* b_gcn = (const float*)d_in[2];
    const float* bn1_g = (const float*)d_in[3];
    const float* bn1_b = (const float*)d_in[4];
    const float* bn2_g = (const float*)d_in[5];
    const float* bn2_b = (const float*)d_in[6];
    const float* ff_w1 = (const float*)d_in[7];
    const float* ff_b1 = (const float*)d_in[8];
    const float* ff_w2 = (const float*)d_in[9];
    const float* cls_w = (const float*)d_in[10];
    const float* cls_b = (const float*)d_in[11];
    const int* esrc = (const int*)d_in[12];
    const int* edst = (const int*)d_in[13];
    const int N = in_sizes[0] / 128;
    const int E = in_sizes[12];
    const int M_pad = (N + 127) & ~127;

    char* p = (char*)d_ws;
    auto alloc = [&](size_t bytes) {
        void* r = (void*)p;
        p += (bytes + 255) & ~(size_t)255;
        return r;
    };
    // zero-region: cnt | cursor | 4x sums  (one memset)
    int* cnt      = (int*)alloc((size_t)N * 4);
    int* cursor   = (int*)alloc((size_t)N * 4);
    float* sums4  = (float*)alloc(4 * 256 * 4);
    size_t zbytes = (size_t)((char*)sums4 + 4 * 256 * 4 - (char*)cnt);

    float* t    = (float*)alloc((size_t)M_pad * 128 * 4);
    int* rowptr = (int*)alloc((size_t)(N + 1) * 4);
    int* srcs   = (int*)alloc((size_t)E * 4);
    int* bsum   = (int*)alloc(SCAN_G * 4);
    int* boff   = (int*)alloc(SCAN_G * 4);
    unsigned short* nodes_bf = (unsigned short*)alloc((size_t)M_pad * 128 * 2);
    unsigned short* agg_bf   = (unsigned short*)alloc((size_t)M_pad * 128 * 2);
    unsigned short* x_bf     = (unsigned short*)alloc((size_t)M_pad * 128 * 2);
    unsigned short* WgT = (unsigned short*)alloc(2 * 128 * 128 * 2);
    unsigned short* W1T = (unsigned short*)alloc(2 * 512 * 128 * 2);
    unsigned short* W2T = (unsigned short*)alloc(2 * 128 * 512 * 2);
    unsigned short* WcT = (unsigned short*)alloc(16 * 128 * 2);

    hipMemsetAsync(cnt, 0, zbytes, stream);
    k_count<<<(E + 255) / 256, 256, 0, stream>>>(edst, cnt, E);
    k_scanA<<<SCAN_G, 256, 0, stream>>>(cnt, bsum, N);
    k_scanB<<<1, SCAN_G, 0, stream>>>(bsum, boff, rowptr, N);
    k_scanC<<<SCAN_G, 256, 0, stream>>>(cnt, boff, rowptr, N);
    k_fill<<<(E + 255) / 256, 256, 0, stream>>>(esrc, edst, rowptr, cursor, srcs, E);
    k_convw<<<1160, 256, 0, stream>>>(W_gcn, ff_w1, ff_w2, cls_w, WgT, W1T, W2T, WcT);
    k_convn<<<1600, 256, 0, stream>>>(nodes, nodes_bf, N * 64);

    const float invN = 1.0f / (float)N;
    const int MB = M_pad / 128;
    const int MB64 = M_pad / 64;
    const unsigned short* cur_bf = nodes_bf;
    for (int L = 0; L < 2; ++L) {
        k_agg<<<(N + 7) / 8, 256, 0, stream>>>(cur_bf, rowptr, srcs, agg_bf, N);
        float* s1 = sums4 + (L * 2 + 0) * 256;
        float* s2 = sums4 + (L * 2 + 1) * 256;
        // GCN: t = agg@Wg + b + res(cur_bf), f32 out, fused BN1 stats
        k_mgemm<false, true, true, false, true><<<dim3(MB, 1), 256, 0, stream>>>(
            agg_bf, WgT + (size_t)L * 16384, b_gcn + L * 128, cur_bf, t, nullptr, s1,
            N, 128, 128);
        // fused: bn1-apply + FF1 + FF2 + residual + BN2 stats (y in registers)
        k_ffused<<<MB64, 256, 0, stream>>>(
            t, s1, bn1_g + L * 128, bn1_b + L * 128,
            W1T + (size_t)L * 65536, ff_b1 + L * 512, W2T + (size_t)L * 65536,
            s2, N, invN);
        k_bnapply<<<1600, 256, 0, stream>>>(t, s2, bn2_g + L * 128, bn2_b + L * 128,
                                            x_bf, N, invN);
        cur_bf = x_bf;
    }
    k_cls<<<(M_pad / 16 + 3) / 4, 256, 0, stream>>>(x_bf, WcT, cls_b, (float*)d_out, N);
}